// Round 3
// baseline (738.294 us; speedup 1.0000x reference)
//
#include <hip/hip_runtime.h>
#include <stdint.h>
#include <math.h>

#define FIN 128

// ---------------- bf16 helpers (manual, RNE) ----------------
__device__ __forceinline__ float2 bf2_to_f2(uint32_t u) {
    union { uint32_t i; float f; } a, b;
    a.i = (u & 0xFFFFu) << 16;
    b.i = u & 0xFFFF0000u;
    return make_float2(a.f, b.f);
}
__device__ __forceinline__ uint32_t f2_to_bf2(float x, float y) {
    union { float f; uint32_t i; } a, b;
    a.f = x; b.f = y;
    uint32_t ax = a.i + 0x7FFF + ((a.i >> 16) & 1);
    uint32_t by = b.i + 0x7FFF + ((b.i >> 16) & 1);
    return (ax >> 16) | (by & 0xFFFF0000u);
}

// ---------------- edge dtype detection ----------------
__global__ __launch_bounds__(256) void detect_kernel(const int* __restrict__ ei32,
                                                     int* __restrict__ flag, int nsamp) {
    int i = blockIdx.x * 256 + threadIdx.x;
    if (i < nsamp) {
        if (ei32[2 * i + 1] != 0) atomicOr(flag, 1);
    }
}

__device__ __forceinline__ int edge_at(const void* ei, long long idx, int is32) {
    return is32 ? ((const int*)ei)[idx] : (int)((const long long*)ei)[idx];
}

// ---------------- Pass A: bin edges by dst>>6 into fixed-cap buckets ----------------
// record = (src << 6) | (dst & 63). Writes land sequentially per bin -> dense lines.
__global__ __launch_bounds__(256) void binA_kernel(const void* __restrict__ ei,
                                                   const int* __restrict__ flag,
                                                   int* __restrict__ binCnt,
                                                   uint32_t* __restrict__ binBuf,
                                                   int E, int cap) {
    int e = blockIdx.x * 256 + threadIdx.x;
    if (e >= E) return;
    int is32 = *flag;
    int s = edge_at(ei, e, is32);
    int d = edge_at(ei, (long long)E + e, is32);
    int bin = d >> 6;
    int pos = atomicAdd(&binCnt[bin], 1);
    if (pos < cap)
        binBuf[(size_t)bin * cap + pos] = ((uint32_t)s << 6) | (uint32_t)(d & 63);
}

// ---------------- Pass B: per-node degree via LDS histogram (one bin per block) ----
__global__ __launch_bounds__(256) void binB_kernel(const int* __restrict__ binCnt,
                                                   const uint32_t* __restrict__ binBuf,
                                                   int* __restrict__ cnt, int n, int cap) {
    __shared__ int h[64];
    int bin = blockIdx.x;
    int t = threadIdx.x;
    if (t < 64) h[t] = 0;
    __syncthreads();
    int m = binCnt[bin];
    if (m > cap) m = cap;
    const uint32_t* buf = binBuf + (size_t)bin * cap;
    for (int i = t; i < m; i += 256) atomicAdd(&h[buf[i] & 63], 1);
    __syncthreads();
    if (t < 64) {
        int node = bin * 64 + t;
        if (node < n) cnt[node] = h[t];
    }
}

// ---------------- 3-phase scan (inclusive) ----------------
#define SCAN_BS 1024
__global__ __launch_bounds__(SCAN_BS) void scan_phaseA(const int* __restrict__ cnt,
                                                       int* __restrict__ incl,
                                                       int* __restrict__ bsums, int n) {
    __shared__ int sm[SCAN_BS];
    int gid = blockIdx.x * SCAN_BS + threadIdx.x;
    int v = (gid < n) ? cnt[gid] : 0;
    sm[threadIdx.x] = v;
    __syncthreads();
    for (int off = 1; off < SCAN_BS; off <<= 1) {
        int t = 0;
        if ((int)threadIdx.x >= off) t = sm[threadIdx.x - off];
        __syncthreads();
        sm[threadIdx.x] += t;
        __syncthreads();
    }
    if (gid < n) incl[gid] = sm[threadIdx.x];
    if (threadIdx.x == SCAN_BS - 1) bsums[blockIdx.x] = sm[threadIdx.x];
}

__global__ __launch_bounds__(128) void scan_phaseB(int* __restrict__ bsums, int nb) {
    __shared__ int sm[128];
    int v = ((int)threadIdx.x < nb) ? bsums[threadIdx.x] : 0;
    sm[threadIdx.x] = v;
    __syncthreads();
    for (int off = 1; off < 128; off <<= 1) {
        int t = 0;
        if ((int)threadIdx.x >= off) t = sm[threadIdx.x - off];
        __syncthreads();
        sm[threadIdx.x] += t;
        __syncthreads();
    }
    if ((int)threadIdx.x < nb)
        bsums[threadIdx.x] = (threadIdx.x == 0) ? 0 : sm[threadIdx.x - 1];
}

__global__ __launch_bounds__(256) void scan_phaseC(int* __restrict__ incl,
                                                   const int* __restrict__ bsums, int n) {
    int gid = blockIdx.x * 256 + threadIdx.x;
    if (gid < n) incl[gid] += bsums[gid >> 10];
}

// ---------------- dinv = rsqrt(deg), deg = cnt + 1 (self loop) ----------------
__global__ __launch_bounds__(256) void dinv_kernel(const int* __restrict__ cnt,
                                                   float* __restrict__ dinv, int n) {
    int i = blockIdx.x * 256 + threadIdx.x;
    if (i < n) dinv[i] = rsqrtf((float)cnt[i] + 1.0f);
}

// ---------------- Pass C: scatter bin records into CSR (LDS cursors) -------------
// Each bin's CSR window is contiguous (~4KB) -> dense write lines.
__global__ __launch_bounds__(256) void binC_kernel(const int* __restrict__ binCnt,
                                                   const uint32_t* __restrict__ binBuf,
                                                   const int* __restrict__ rowend,
                                                   const int* __restrict__ cnt,
                                                   int* __restrict__ col, int n, int cap) {
    __shared__ int rowst[64];
    __shared__ int cur[64];
    int bin = blockIdx.x;
    int t = threadIdx.x;
    if (t < 64) {
        cur[t] = 0;
        int node = bin * 64 + t;
        rowst[t] = (node < n) ? rowend[node] - cnt[node] : 0;
    }
    __syncthreads();
    int m = binCnt[bin];
    if (m > cap) m = cap;
    const uint32_t* buf = binBuf + (size_t)bin * cap;
    for (int i = t; i < m; i += 256) {
        uint32_t rec = buf[i];
        int d6 = rec & 63;
        int off = atomicAdd(&cur[d6], 1);
        col[rowst[d6] + off] = (int)(rec >> 6);
    }
}

// ---------------- fp32 GEMM: C[n x NCOL] = A[n x 128] @ W[128 x NCOL] ----------------
template <int NCOL, int CPT, int OUT_BF16>
__global__ __launch_bounds__(256) void gemm_k128(const float* __restrict__ A,
                                                 const float* __restrict__ W,
                                                 void* __restrict__ Cv, int n) {
    __shared__ float Asub[64 * 33];
    __shared__ float Wsub[32 * NCOL];
    const int t = threadIdx.x;
    const int tc = t & 15;
    const int tr = t >> 4;
    const int row0 = blockIdx.x * 64;

    float acc[4][CPT];
#pragma unroll
    for (int i = 0; i < 4; ++i)
#pragma unroll
        for (int c = 0; c < CPT; ++c) acc[i][c] = 0.0f;

    for (int kc = 0; kc < 128; kc += 32) {
#pragma unroll
        for (int i = 0; i < 2; ++i) {
            int s = t + i * 256;
            int r = s >> 3, kq = s & 7;
            int gr = row0 + r;
            gr = gr < n ? gr : n - 1;
            float4 v = *(const float4*)(A + (size_t)gr * FIN + kc + kq * 4);
            Asub[r * 33 + kq * 4 + 0] = v.x;
            Asub[r * 33 + kq * 4 + 1] = v.y;
            Asub[r * 33 + kq * 4 + 2] = v.z;
            Asub[r * 33 + kq * 4 + 3] = v.w;
        }
#pragma unroll
        for (int i = 0; i < NCOL / 32; ++i) {
            int s = t + i * 256;
            int k = s / (NCOL / 4);
            int cq = s % (NCOL / 4);
            *(float4*)(Wsub + k * NCOL + cq * 4) =
                *(const float4*)(W + (size_t)(kc + k) * NCOL + cq * 4);
        }
        __syncthreads();
#pragma unroll 8
        for (int k = 0; k < 32; ++k) {
            float b[CPT];
            {
                float4 b0 = *(const float4*)(Wsub + k * NCOL + tc * 4);
                b[0] = b0.x; b[1] = b0.y; b[2] = b0.z; b[3] = b0.w;
                if (CPT == 8) {
                    float4 b1 = *(const float4*)(Wsub + k * NCOL + 64 + tc * 4);
                    b[4] = b1.x; b[5] = b1.y; b[6] = b1.z; b[7] = b1.w;
                }
            }
            float a[4];
#pragma unroll
            for (int i = 0; i < 4; ++i) a[i] = Asub[(tr * 4 + i) * 33 + k];
#pragma unroll
            for (int i = 0; i < 4; ++i)
#pragma unroll
                for (int c = 0; c < CPT; ++c) acc[i][c] += a[i] * b[c];
        }
        __syncthreads();
    }
#pragma unroll
    for (int i = 0; i < 4; ++i) {
        int gr = row0 + tr * 4 + i;
        if (gr >= n) continue;
        if (OUT_BF16) {
            unsigned short* C = (unsigned short*)Cv;
            uint2 v0;
            v0.x = f2_to_bf2(acc[i][0], acc[i][1]);
            v0.y = f2_to_bf2(acc[i][2], acc[i][3]);
            *(uint2*)(C + (size_t)gr * NCOL + tc * 4) = v0;
            if (CPT == 8) {
                uint2 v1;
                v1.x = f2_to_bf2(acc[i][4], acc[i][5]);
                v1.y = f2_to_bf2(acc[i][6], acc[i][7]);
                *(uint2*)(C + (size_t)gr * NCOL + 64 + tc * 4) = v1;
            }
        } else {
            float* C = (float*)Cv;
            float4 v0 = make_float4(acc[i][0], acc[i][1], acc[i][2], acc[i][3]);
            *(float4*)(C + (size_t)gr * NCOL + tc * 4) = v0;
            if (CPT == 8) {
                float4 v1 = make_float4(acc[i][4], acc[i][5], acc[i][6], acc[i][7]);
                *(float4*)(C + (size_t)gr * NCOL + 64 + tc * 4) = v1;
            }
        }
    }
}

// ---------------- aggregation, width 128, bf16 T ----------------
__global__ __launch_bounds__(256) void agg_relu_128_bf16(
        const unsigned short* __restrict__ T, const int* __restrict__ rowend,
        const int* __restrict__ cnt, const int* __restrict__ col,
        const float* __restrict__ dinv, const float* __restrict__ bias,
        float* __restrict__ out, int n, int do_relu) {
    int node = blockIdx.x * 4 + (threadIdx.x >> 6);
    if (node >= n) return;
    int lane = threadIdx.x & 63;
    int end = rowend[node];
    int start = end - cnt[node];
    float di = dinv[node];
    float2 sv = bf2_to_f2(((const uint32_t*)(T + (size_t)node * 128))[lane]);
    float acc0 = sv.x * di;
    float acc1 = sv.y * di;
    int p = start;
    for (; p + 8 <= end; p += 8) {
        int s0 = col[p + 0], s1 = col[p + 1], s2 = col[p + 2], s3 = col[p + 3];
        int s4 = col[p + 4], s5 = col[p + 5], s6 = col[p + 6], s7 = col[p + 7];
        float w0 = dinv[s0], w1 = dinv[s1], w2 = dinv[s2], w3 = dinv[s3];
        float w4 = dinv[s4], w5 = dinv[s5], w6 = dinv[s6], w7 = dinv[s7];
        uint32_t u0 = ((const uint32_t*)(T + (size_t)s0 * 128))[lane];
        uint32_t u1 = ((const uint32_t*)(T + (size_t)s1 * 128))[lane];
        uint32_t u2 = ((const uint32_t*)(T + (size_t)s2 * 128))[lane];
        uint32_t u3 = ((const uint32_t*)(T + (size_t)s3 * 128))[lane];
        uint32_t u4 = ((const uint32_t*)(T + (size_t)s4 * 128))[lane];
        uint32_t u5 = ((const uint32_t*)(T + (size_t)s5 * 128))[lane];
        uint32_t u6 = ((const uint32_t*)(T + (size_t)s6 * 128))[lane];
        uint32_t u7 = ((const uint32_t*)(T + (size_t)s7 * 128))[lane];
        float2 v;
        v = bf2_to_f2(u0); acc0 += w0 * v.x; acc1 += w0 * v.y;
        v = bf2_to_f2(u1); acc0 += w1 * v.x; acc1 += w1 * v.y;
        v = bf2_to_f2(u2); acc0 += w2 * v.x; acc1 += w2 * v.y;
        v = bf2_to_f2(u3); acc0 += w3 * v.x; acc1 += w3 * v.y;
        v = bf2_to_f2(u4); acc0 += w4 * v.x; acc1 += w4 * v.y;
        v = bf2_to_f2(u5); acc0 += w5 * v.x; acc1 += w5 * v.y;
        v = bf2_to_f2(u6); acc0 += w6 * v.x; acc1 += w6 * v.y;
        v = bf2_to_f2(u7); acc0 += w7 * v.x; acc1 += w7 * v.y;
    }
    for (; p < end; ++p) {
        int s = col[p];
        float w = dinv[s];
        float2 v = bf2_to_f2(((const uint32_t*)(T + (size_t)s * 128))[lane]);
        acc0 += w * v.x;
        acc1 += w * v.y;
    }
    float2 b2 = ((const float2*)bias)[lane];
    float v0 = di * acc0 + b2.x;
    float v1 = di * acc1 + b2.y;
    if (do_relu) { v0 = fmaxf(v0, 0.0f); v1 = fmaxf(v1, 0.0f); }
    *(float2*)(out + (size_t)node * 128 + 2 * lane) = make_float2(v0, v1);
}

// ---------------- aggregation width 64 (fp32 T) + bias + log_softmax ----------------
__global__ __launch_bounds__(256) void agg_lsm_64(const float* __restrict__ T,
                                                  const int* __restrict__ rowend,
                                                  const int* __restrict__ cnt,
                                                  const int* __restrict__ col,
                                                  const float* __restrict__ dinv,
                                                  const float* __restrict__ bias,
                                                  float* __restrict__ out, int n) {
    int node = blockIdx.x * 4 + (threadIdx.x >> 6);
    if (node >= n) return;
    int lane = threadIdx.x & 63;
    int end = rowend[node];
    int start = end - cnt[node];
    float di = dinv[node];
    float acc = T[(size_t)node * 64 + lane] * di;
    int p = start;
    for (; p + 4 <= end; p += 4) {
        int s0 = col[p], s1 = col[p + 1], s2 = col[p + 2], s3 = col[p + 3];
        float w0 = dinv[s0], w1 = dinv[s1], w2 = dinv[s2], w3 = dinv[s3];
        acc += w0 * T[(size_t)s0 * 64 + lane];
        acc += w1 * T[(size_t)s1 * 64 + lane];
        acc += w2 * T[(size_t)s2 * 64 + lane];
        acc += w3 * T[(size_t)s3 * 64 + lane];
    }
    for (; p < end; ++p) {
        int s = col[p];
        acc += dinv[s] * T[(size_t)s * 64 + lane];
    }
    float r = di * acc + bias[lane];
    float m = r;
    for (int o = 32; o > 0; o >>= 1) m = fmaxf(m, __shfl_xor(m, o, 64));
    float e = expf(r - m);
    float ssum = e;
    for (int o = 32; o > 0; o >>= 1) ssum += __shfl_xor(ssum, o, 64);
    out[(size_t)node * 64 + lane] = r - m - logf(ssum);
}

// ---------------- launcher ----------------
extern "C" void kernel_launch(void* const* d_in, const int* in_sizes, int n_in,
                              void* d_out, int out_size, void* d_ws, size_t ws_size,
                              hipStream_t stream) {
    const float* x  = (const float*)d_in[0];
    const void*  ei = d_in[1];
    const float* W1 = (const float*)d_in[2];
    const float* b1 = (const float*)d_in[3];
    const float* W2 = (const float*)d_in[4];
    const float* b2 = (const float*)d_in[5];
    const float* W3 = (const float*)d_in[6];
    const float* b3 = (const float*)d_in[7];
    float* out = (float*)d_out;

    const int n = in_sizes[0] / FIN;       // 100000
    const int E = in_sizes[1] / 2;         // 1600000

    char* p = (char*)d_ws;
    auto carve = [&](size_t bytes) {
        char* q = p;
        p += (bytes + 255) & ~(size_t)255;
        return q;
    };
    int*   cnt    = (int*)carve((size_t)n * 4);
    int*   flag   = (int*)carve(256);
    int*   rowend = (int*)carve((size_t)n * 4);
    int*   bsums  = (int*)carve(1024 * 4);
    float* dinv   = (float*)carve((size_t)n * 4);
    int*   colb   = (int*)carve((size_t)E * 4);
    // T: bf16 n*128 (25.6MB) layers 1-2; fp32 n*64 layer 3. binBuf aliases T
    // (free during preprocessing).
    size_t Tbytes = (size_t)n * 128 * 2 > (size_t)n * 64 * 4
                        ? (size_t)n * 128 * 2 : (size_t)n * 64 * 4;
    void*  T      = (void*)carve(Tbytes);
    float* Hb     = (float*)carve((size_t)n * 128 * 4);

    const int NB = (n + 63) / 64;                 // bins of 64 dst nodes
    int*       binCnt = (int*)carve((size_t)NB * 4);
    uint32_t*  binBuf = (uint32_t*)T;             // alias

    // bucket capacity: mean + 8 sigma + pad, clamped to the T region
    int meanB = E / NB;
    int cap = meanB + 8 * (int)sqrt((double)meanB) + 64;
    cap = (cap + 15) & ~15;
    size_t maxcap = Tbytes / ((size_t)NB * 4);
    if ((size_t)cap > maxcap) cap = (int)maxcap;

    hipMemsetAsync(flag, 0, 4, stream);
    hipMemsetAsync(binCnt, 0, (size_t)NB * 4, stream);

    const int gE = (E + 255) / 256;
    const int g256 = (n + 255) / 256;
    const int nbA = (n + SCAN_BS - 1) / SCAN_BS;
    const int gagg = (n + 3) / 4;
    const int ggemm = (n + 63) / 64;
    const int nsamp = E < 65536 ? E : 65536;

    detect_kernel<<<(nsamp + 255) / 256, 256, 0, stream>>>((const int*)ei, flag, nsamp);
    binA_kernel<<<gE, 256, 0, stream>>>(ei, flag, binCnt, binBuf, E, cap);
    binB_kernel<<<NB, 256, 0, stream>>>(binCnt, binBuf, cnt, n, cap);
    scan_phaseA<<<nbA, SCAN_BS, 0, stream>>>(cnt, rowend, bsums, n);
    scan_phaseB<<<1, 128, 0, stream>>>(bsums, nbA);
    scan_phaseC<<<g256, 256, 0, stream>>>(rowend, bsums, n);
    dinv_kernel<<<g256, 256, 0, stream>>>(cnt, dinv, n);
    binC_kernel<<<NB, 256, 0, stream>>>(binCnt, binBuf, rowend, cnt, colb, n, cap);

    // layer 1: T(bf16) = x @ W1 ; Hb = relu(agg(T) + b1)
    gemm_k128<128, 8, 1><<<ggemm, 256, 0, stream>>>(x, W1, T, n);
    agg_relu_128_bf16<<<gagg, 256, 0, stream>>>((const unsigned short*)T, rowend, cnt,
                                                colb, dinv, b1, Hb, n, 1);
    // layer 2: T(bf16) = Hb @ W2 ; Hb = relu(agg(T) + b2)
    gemm_k128<128, 8, 1><<<ggemm, 256, 0, stream>>>(Hb, W2, T, n);
    agg_relu_128_bf16<<<gagg, 256, 0, stream>>>((const unsigned short*)T, rowend, cnt,
                                                colb, dinv, b2, Hb, n, 1);
    // layer 3: T(fp32) = Hb @ W3 ; out = log_softmax(agg(T) + b3)
    gemm_k128<64, 4, 0><<<ggemm, 256, 0, stream>>>(Hb, W3, T, n);
    agg_lsm_64<<<gagg, 256, 0, stream>>>((const float*)T, rowend, cnt, colb, dinv, b3,
                                         out, n);
}

// Round 4
// 531.335 us; speedup vs baseline: 1.3895x; 1.3895x over previous
//
#include <hip/hip_runtime.h>
#include <stdint.h>
#include <math.h>

#define FIN 128

// ---------------- bf16 helpers (manual, RNE) ----------------
__device__ __forceinline__ float2 bf2_to_f2(uint32_t u) {
    union { uint32_t i; float f; } a, b;
    a.i = (u & 0xFFFFu) << 16;
    b.i = u & 0xFFFF0000u;
    return make_float2(a.f, b.f);
}
__device__ __forceinline__ float bf_to_f(unsigned short u) {
    union { uint32_t i; float f; } a;
    a.i = ((uint32_t)u) << 16;
    return a.f;
}
__device__ __forceinline__ uint32_t f2_to_bf2(float x, float y) {
    union { float f; uint32_t i; } a, b;
    a.f = x; b.f = y;
    uint32_t ax = a.i + 0x7FFF + ((a.i >> 16) & 1);
    uint32_t by = b.i + 0x7FFF + ((b.i >> 16) & 1);
    return (ax >> 16) | (by & 0xFFFF0000u);
}

// ---------------- edge dtype detection ----------------
__global__ __launch_bounds__(256) void detect_kernel(const int* __restrict__ ei32,
                                                     int* __restrict__ flag, int nsamp) {
    int i = blockIdx.x * 256 + threadIdx.x;
    if (i < nsamp) {
        if (ei32[2 * i + 1] != 0) atomicOr(flag, 1);
    }
}

__device__ __forceinline__ int edge_at(const void* ei, long long idx, int is32) {
    return is32 ? ((const int*)ei)[idx] : (int)((const long long*)ei)[idx];
}

// ---------------- Level-1 split: 16 super-bins (dst>>13), LDS hist + block reserve ---
// Block-private contiguous runs per bucket -> dense write lines, ~16 global atomics/block.
#define SP_CHUNK 4096
__global__ __launch_bounds__(256) void splitA_kernel(const void* __restrict__ ei,
                                                     const int* __restrict__ flag,
                                                     int* __restrict__ gCnt,
                                                     uint2* __restrict__ buf1,
                                                     int E, int capS) {
    __shared__ int hist[16];
    __shared__ int gbase[16];
    int t = threadIdx.x;
    if (t < 16) hist[t] = 0;
    __syncthreads();
    int is32 = *flag;
    long long base = (long long)blockIdx.x * SP_CHUNK;
    uint32_t lrec[16], rs[16], rd[16];
#pragma unroll
    for (int j = 0; j < 16; ++j) {
        long long e = base + t + j * 256;
        if (e < E) {
            int s = edge_at(ei, e, is32);
            int d = edge_at(ei, (long long)E + e, is32);
            int b = d >> 13;
            int lofs = atomicAdd(&hist[b], 1);
            lrec[j] = ((uint32_t)lofs << 4) | (uint32_t)b;
            rs[j] = (uint32_t)s;
            rd[j] = (uint32_t)d;
        } else
            lrec[j] = 0xFFFFFFFFu;
    }
    __syncthreads();
    if (t < 16) gbase[t] = atomicAdd(&gCnt[t], hist[t]);
    __syncthreads();
#pragma unroll
    for (int j = 0; j < 16; ++j) {
        if (lrec[j] != 0xFFFFFFFFu) {
            int b = lrec[j] & 15;
            int pos = gbase[b] + (int)(lrec[j] >> 4);
            if (pos < capS) buf1[(size_t)b * capS + pos] = make_uint2(rs[j], rd[j]);
        }
    }
}

// ---------------- Level-2 split: 128 sub-bins of 64 nodes within a super-bin --------
__global__ __launch_bounds__(256) void splitB_kernel(const int* __restrict__ gCnt,
                                                     const uint2* __restrict__ buf1,
                                                     int* __restrict__ cnt2,
                                                     uint32_t* __restrict__ buf2,
                                                     int capS, int cap2, int NB) {
    __shared__ int hist[128];
    __shared__ int gbase[128];
    int t = threadIdx.x;
    int s = blockIdx.y;
    if (t < 128) hist[t] = 0;
    __syncthreads();
    int m = gCnt[s];
    if (m > capS) m = capS;
    long long base = (long long)blockIdx.x * SP_CHUNK;
    uint32_t lrec[16], r32[16];
#pragma unroll
    for (int j = 0; j < 16; ++j) {
        long long i = base + t + j * 256;
        if (i < m) {
            uint2 r = buf1[(size_t)s * capS + i];
            int d = (int)r.y;
            int sub = (d >> 6) & 127;
            int lofs = atomicAdd(&hist[sub], 1);
            lrec[j] = ((uint32_t)lofs << 7) | (uint32_t)sub;
            r32[j] = (r.x << 6) | (uint32_t)(d & 63);
        } else
            lrec[j] = 0xFFFFFFFFu;
    }
    __syncthreads();
    if (t < 128) {
        int g = s * 128 + t;
        gbase[t] = (g < NB) ? atomicAdd(&cnt2[g], hist[t]) : 0;
    }
    __syncthreads();
#pragma unroll
    for (int j = 0; j < 16; ++j) {
        if (lrec[j] != 0xFFFFFFFFu) {
            int sub = lrec[j] & 127;
            int pos = gbase[sub] + (int)(lrec[j] >> 7);
            if (pos < cap2) buf2[(size_t)(s * 128 + sub) * cap2 + pos] = r32[j];
        }
    }
}

// ---------------- per-node degree via LDS histogram (one 64-node bin per block) ----
__global__ __launch_bounds__(256) void binB_kernel(const int* __restrict__ cnt2,
                                                   const uint32_t* __restrict__ buf2,
                                                   int* __restrict__ cnt, int n, int cap2) {
    __shared__ int h[64];
    int bin = blockIdx.x;
    int t = threadIdx.x;
    if (t < 64) h[t] = 0;
    __syncthreads();
    int m = cnt2[bin];
    if (m > cap2) m = cap2;
    const uint32_t* buf = buf2 + (size_t)bin * cap2;
    for (int i = t; i < m; i += 256) atomicAdd(&h[buf[i] & 63], 1);
    __syncthreads();
    if (t < 64) {
        int node = bin * 64 + t;
        if (node < n) cnt[node] = h[t];
    }
}

// ---------------- 3-phase scan (inclusive) ----------------
#define SCAN_BS 1024
__global__ __launch_bounds__(SCAN_BS) void scan_phaseA(const int* __restrict__ cnt,
                                                       int* __restrict__ incl,
                                                       int* __restrict__ bsums, int n) {
    __shared__ int sm[SCAN_BS];
    int gid = blockIdx.x * SCAN_BS + threadIdx.x;
    int v = (gid < n) ? cnt[gid] : 0;
    sm[threadIdx.x] = v;
    __syncthreads();
    for (int off = 1; off < SCAN_BS; off <<= 1) {
        int t = 0;
        if ((int)threadIdx.x >= off) t = sm[threadIdx.x - off];
        __syncthreads();
        sm[threadIdx.x] += t;
        __syncthreads();
    }
    if (gid < n) incl[gid] = sm[threadIdx.x];
    if (threadIdx.x == SCAN_BS - 1) bsums[blockIdx.x] = sm[threadIdx.x];
}

__global__ __launch_bounds__(128) void scan_phaseB(int* __restrict__ bsums, int nb) {
    __shared__ int sm[128];
    int v = ((int)threadIdx.x < nb) ? bsums[threadIdx.x] : 0;
    sm[threadIdx.x] = v;
    __syncthreads();
    for (int off = 1; off < 128; off <<= 1) {
        int t = 0;
        if ((int)threadIdx.x >= off) t = sm[threadIdx.x - off];
        __syncthreads();
        sm[threadIdx.x] += t;
        __syncthreads();
    }
    if ((int)threadIdx.x < nb)
        bsums[threadIdx.x] = (threadIdx.x == 0) ? 0 : sm[threadIdx.x - 1];
}

__global__ __launch_bounds__(256) void scan_phaseC(int* __restrict__ incl,
                                                   const int* __restrict__ bsums, int n) {
    int gid = blockIdx.x * 256 + threadIdx.x;
    if (gid < n) incl[gid] += bsums[gid >> 10];
}

// ---------------- dinv = rsqrt(deg), deg = cnt + 1 (self loop) ----------------
__global__ __launch_bounds__(256) void dinv_kernel(const int* __restrict__ cnt,
                                                   float* __restrict__ dinv, int n) {
    int i = blockIdx.x * 256 + threadIdx.x;
    if (i < n) dinv[i] = rsqrtf((float)cnt[i] + 1.0f);
}

// ---------------- scatter bin records into CSR (LDS cursors, dense windows) -------
__global__ __launch_bounds__(256) void binC_kernel(const int* __restrict__ cnt2,
                                                   const uint32_t* __restrict__ buf2,
                                                   const int* __restrict__ rowend,
                                                   const int* __restrict__ cnt,
                                                   int* __restrict__ col, int n, int cap2) {
    __shared__ int rowst[64];
    __shared__ int cur[64];
    int bin = blockIdx.x;
    int t = threadIdx.x;
    if (t < 64) {
        cur[t] = 0;
        int node = bin * 64 + t;
        rowst[t] = (node < n) ? rowend[node] - cnt[node] : 0;
    }
    __syncthreads();
    int m = cnt2[bin];
    if (m > cap2) m = cap2;
    const uint32_t* buf = buf2 + (size_t)bin * cap2;
    for (int i = t; i < m; i += 256) {
        uint32_t rec = buf[i];
        int d6 = rec & 63;
        int off = atomicAdd(&cur[d6], 1);
        col[rowst[d6] + off] = (int)(rec >> 6);
    }
}

// ---------------- fp32 GEMM: C[n x NCOL] = A[n x 128] @ W[128 x NCOL] ----------------
template <int NCOL, int CPT, int OUT_BF16>
__global__ __launch_bounds__(256) void gemm_k128(const float* __restrict__ A,
                                                 const float* __restrict__ W,
                                                 void* __restrict__ Cv, int n) {
    __shared__ float Asub[64 * 33];
    __shared__ float Wsub[32 * NCOL];
    const int t = threadIdx.x;
    const int tc = t & 15;
    const int tr = t >> 4;
    const int row0 = blockIdx.x * 64;

    float acc[4][CPT];
#pragma unroll
    for (int i = 0; i < 4; ++i)
#pragma unroll
        for (int c = 0; c < CPT; ++c) acc[i][c] = 0.0f;

    for (int kc = 0; kc < 128; kc += 32) {
#pragma unroll
        for (int i = 0; i < 2; ++i) {
            int s = t + i * 256;
            int r = s >> 3, kq = s & 7;
            int gr = row0 + r;
            gr = gr < n ? gr : n - 1;
            float4 v = *(const float4*)(A + (size_t)gr * FIN + kc + kq * 4);
            Asub[r * 33 + kq * 4 + 0] = v.x;
            Asub[r * 33 + kq * 4 + 1] = v.y;
            Asub[r * 33 + kq * 4 + 2] = v.z;
            Asub[r * 33 + kq * 4 + 3] = v.w;
        }
#pragma unroll
        for (int i = 0; i < NCOL / 32; ++i) {
            int s = t + i * 256;
            int k = s / (NCOL / 4);
            int cq = s % (NCOL / 4);
            *(float4*)(Wsub + k * NCOL + cq * 4) =
                *(const float4*)(W + (size_t)(kc + k) * NCOL + cq * 4);
        }
        __syncthreads();
#pragma unroll 8
        for (int k = 0; k < 32; ++k) {
            float b[CPT];
            {
                float4 b0 = *(const float4*)(Wsub + k * NCOL + tc * 4);
                b[0] = b0.x; b[1] = b0.y; b[2] = b0.z; b[3] = b0.w;
                if (CPT == 8) {
                    float4 b1 = *(const float4*)(Wsub + k * NCOL + 64 + tc * 4);
                    b[4] = b1.x; b[5] = b1.y; b[6] = b1.z; b[7] = b1.w;
                }
            }
            float a[4];
#pragma unroll
            for (int i = 0; i < 4; ++i) a[i] = Asub[(tr * 4 + i) * 33 + k];
#pragma unroll
            for (int i = 0; i < 4; ++i)
#pragma unroll
                for (int c = 0; c < CPT; ++c) acc[i][c] += a[i] * b[c];
        }
        __syncthreads();
    }
#pragma unroll
    for (int i = 0; i < 4; ++i) {
        int gr = row0 + tr * 4 + i;
        if (gr >= n) continue;
        if (OUT_BF16) {
            unsigned short* C = (unsigned short*)Cv;
            uint2 v0;
            v0.x = f2_to_bf2(acc[i][0], acc[i][1]);
            v0.y = f2_to_bf2(acc[i][2], acc[i][3]);
            *(uint2*)(C + (size_t)gr * NCOL + tc * 4) = v0;
            if (CPT == 8) {
                uint2 v1;
                v1.x = f2_to_bf2(acc[i][4], acc[i][5]);
                v1.y = f2_to_bf2(acc[i][6], acc[i][7]);
                *(uint2*)(C + (size_t)gr * NCOL + 64 + tc * 4) = v1;
            }
        } else {
            float* C = (float*)Cv;
            float4 v0 = make_float4(acc[i][0], acc[i][1], acc[i][2], acc[i][3]);
            *(float4*)(C + (size_t)gr * NCOL + tc * 4) = v0;
            if (CPT == 8) {
                float4 v1 = make_float4(acc[i][4], acc[i][5], acc[i][6], acc[i][7]);
                *(float4*)(C + (size_t)gr * NCOL + 64 + tc * 4) = v1;
            }
        }
    }
}

// ---------------- aggregation, width 128, bf16 T ----------------
__global__ __launch_bounds__(256) void agg_relu_128_bf16(
        const unsigned short* __restrict__ T, const int* __restrict__ rowend,
        const int* __restrict__ cnt, const int* __restrict__ col,
        const float* __restrict__ dinv, const float* __restrict__ bias,
        float* __restrict__ out, int n, int do_relu) {
    int node = blockIdx.x * 4 + (threadIdx.x >> 6);
    if (node >= n) return;
    int lane = threadIdx.x & 63;
    int end = rowend[node];
    int start = end - cnt[node];
    float di = dinv[node];
    float2 sv = bf2_to_f2(((const uint32_t*)(T + (size_t)node * 128))[lane]);
    float acc0 = sv.x * di;
    float acc1 = sv.y * di;
    int p = start;
    for (; p + 8 <= end; p += 8) {
        int s0 = col[p + 0], s1 = col[p + 1], s2 = col[p + 2], s3 = col[p + 3];
        int s4 = col[p + 4], s5 = col[p + 5], s6 = col[p + 6], s7 = col[p + 7];
        float w0 = dinv[s0], w1 = dinv[s1], w2 = dinv[s2], w3 = dinv[s3];
        float w4 = dinv[s4], w5 = dinv[s5], w6 = dinv[s6], w7 = dinv[s7];
        uint32_t u0 = ((const uint32_t*)(T + (size_t)s0 * 128))[lane];
        uint32_t u1 = ((const uint32_t*)(T + (size_t)s1 * 128))[lane];
        uint32_t u2 = ((const uint32_t*)(T + (size_t)s2 * 128))[lane];
        uint32_t u3 = ((const uint32_t*)(T + (size_t)s3 * 128))[lane];
        uint32_t u4 = ((const uint32_t*)(T + (size_t)s4 * 128))[lane];
        uint32_t u5 = ((const uint32_t*)(T + (size_t)s5 * 128))[lane];
        uint32_t u6 = ((const uint32_t*)(T + (size_t)s6 * 128))[lane];
        uint32_t u7 = ((const uint32_t*)(T + (size_t)s7 * 128))[lane];
        float2 v;
        v = bf2_to_f2(u0); acc0 += w0 * v.x; acc1 += w0 * v.y;
        v = bf2_to_f2(u1); acc0 += w1 * v.x; acc1 += w1 * v.y;
        v = bf2_to_f2(u2); acc0 += w2 * v.x; acc1 += w2 * v.y;
        v = bf2_to_f2(u3); acc0 += w3 * v.x; acc1 += w3 * v.y;
        v = bf2_to_f2(u4); acc0 += w4 * v.x; acc1 += w4 * v.y;
        v = bf2_to_f2(u5); acc0 += w5 * v.x; acc1 += w5 * v.y;
        v = bf2_to_f2(u6); acc0 += w6 * v.x; acc1 += w6 * v.y;
        v = bf2_to_f2(u7); acc0 += w7 * v.x; acc1 += w7 * v.y;
    }
    for (; p < end; ++p) {
        int s = col[p];
        float w = dinv[s];
        float2 v = bf2_to_f2(((const uint32_t*)(T + (size_t)s * 128))[lane]);
        acc0 += w * v.x;
        acc1 += w * v.y;
    }
    float2 b2 = ((const float2*)bias)[lane];
    float v0 = di * acc0 + b2.x;
    float v1 = di * acc1 + b2.y;
    if (do_relu) { v0 = fmaxf(v0, 0.0f); v1 = fmaxf(v1, 0.0f); }
    *(float2*)(out + (size_t)node * 128 + 2 * lane) = make_float2(v0, v1);
}

// ---------------- aggregation width 64 (bf16 T) + bias + log_softmax ----------------
__global__ __launch_bounds__(256) void agg_lsm_64_bf16(
        const unsigned short* __restrict__ T, const int* __restrict__ rowend,
        const int* __restrict__ cnt, const int* __restrict__ col,
        const float* __restrict__ dinv, const float* __restrict__ bias,
        float* __restrict__ out, int n) {
    int node = blockIdx.x * 4 + (threadIdx.x >> 6);
    if (node >= n) return;
    int lane = threadIdx.x & 63;
    int end = rowend[node];
    int start = end - cnt[node];
    float di = dinv[node];
    float acc = bf_to_f(T[(size_t)node * 64 + lane]) * di;
    int p = start;
    for (; p + 8 <= end; p += 8) {
        int s0 = col[p + 0], s1 = col[p + 1], s2 = col[p + 2], s3 = col[p + 3];
        int s4 = col[p + 4], s5 = col[p + 5], s6 = col[p + 6], s7 = col[p + 7];
        float w0 = dinv[s0], w1 = dinv[s1], w2 = dinv[s2], w3 = dinv[s3];
        float w4 = dinv[s4], w5 = dinv[s5], w6 = dinv[s6], w7 = dinv[s7];
        unsigned short u0 = T[(size_t)s0 * 64 + lane];
        unsigned short u1 = T[(size_t)s1 * 64 + lane];
        unsigned short u2 = T[(size_t)s2 * 64 + lane];
        unsigned short u3 = T[(size_t)s3 * 64 + lane];
        unsigned short u4 = T[(size_t)s4 * 64 + lane];
        unsigned short u5 = T[(size_t)s5 * 64 + lane];
        unsigned short u6 = T[(size_t)s6 * 64 + lane];
        unsigned short u7 = T[(size_t)s7 * 64 + lane];
        acc += w0 * bf_to_f(u0) + w1 * bf_to_f(u1) + w2 * bf_to_f(u2) + w3 * bf_to_f(u3);
        acc += w4 * bf_to_f(u4) + w5 * bf_to_f(u5) + w6 * bf_to_f(u6) + w7 * bf_to_f(u7);
    }
    for (; p < end; ++p) {
        int s = col[p];
        acc += dinv[s] * bf_to_f(T[(size_t)s * 64 + lane]);
    }
    float r = di * acc + bias[lane];
    float m = r;
    for (int o = 32; o > 0; o >>= 1) m = fmaxf(m, __shfl_xor(m, o, 64));
    float e = expf(r - m);
    float ssum = e;
    for (int o = 32; o > 0; o >>= 1) ssum += __shfl_xor(ssum, o, 64);
    out[(size_t)node * 64 + lane] = r - m - logf(ssum);
}

// ---------------- launcher ----------------
extern "C" void kernel_launch(void* const* d_in, const int* in_sizes, int n_in,
                              void* d_out, int out_size, void* d_ws, size_t ws_size,
                              hipStream_t stream) {
    const float* x  = (const float*)d_in[0];
    const void*  ei = d_in[1];
    const float* W1 = (const float*)d_in[2];
    const float* b1 = (const float*)d_in[3];
    const float* W2 = (const float*)d_in[4];
    const float* b2 = (const float*)d_in[5];
    const float* W3 = (const float*)d_in[6];
    const float* b3 = (const float*)d_in[7];
    float* out = (float*)d_out;

    const int n = in_sizes[0] / FIN;       // 100000
    const int E = in_sizes[1] / 2;         // 1600000

    char* p = (char*)d_ws;
    auto carve = [&](size_t bytes) {
        char* q = p;
        p += (bytes + 255) & ~(size_t)255;
        return q;
    };
    int*   cnt    = (int*)carve((size_t)n * 4);
    int*   flag   = (int*)carve(256);
    int*   rowend = (int*)carve((size_t)n * 4);
    int*   bsums  = (int*)carve(1024 * 4);
    float* dinv   = (float*)carve((size_t)n * 4);
    int*   colb   = (int*)carve((size_t)E * 4);
    size_t Tbytes = (size_t)n * 128 * 2;   // bf16 n x 128 (layers 1-2); layer-3 bf16 fits
    void*  T      = (void*)carve(Tbytes);
    float* Hb     = (float*)carve((size_t)n * 128 * 4);

    const int NB = (n + 63) / 64;          // 64-node bins
    const int NS = (n + 8191) / 8192;      // 8192-node super-bins
    int*  gCnt = (int*)carve((size_t)16 * 4);
    int*  cnt2 = (int*)carve((size_t)NB * 4);

    // capacities: mean + 8 sigma + pad
    long long meanS = (long long)E * 8192 / n;
    int capS = (int)(meanS + 8 * (long long)sqrt((double)meanS) + 1024);
    capS = (capS + 15) & ~15;
    long long mean2 = (long long)E * 64 / n;
    int cap2 = (int)(mean2 + 8 * (long long)sqrt((double)mean2) + 64);
    cap2 = (cap2 + 15) & ~15;
    // buf1 (uint2) and buf2 (uint32) alias the T region (free during preprocessing)
    size_t buf1B = ((size_t)NS * capS * 8 + 255) & ~(size_t)255;
    uint2*    buf1 = (uint2*)T;
    uint32_t* buf2 = (uint32_t*)((char*)T + buf1B);
    // clamp cap2 so buf2 fits in what's left of T
    size_t avail2 = (Tbytes > buf1B) ? (Tbytes - buf1B) : 0;
    size_t maxc2 = avail2 / ((size_t)NB * 4);
    if ((size_t)cap2 > maxc2) cap2 = (int)maxc2;

    hipMemsetAsync(flag, 0, 4, stream);
    hipMemsetAsync(gCnt, 0, 16 * 4, stream);
    hipMemsetAsync(cnt2, 0, (size_t)NB * 4, stream);

    const int g256 = (n + 255) / 256;
    const int nbA = (n + SCAN_BS - 1) / SCAN_BS;
    const int gagg = (n + 3) / 4;
    const int ggemm = (n + 63) / 64;
    const int nsamp = E < 65536 ? E : 65536;
    const int gsplitA = (E + SP_CHUNK - 1) / SP_CHUNK;
    const int gsplitBx = (capS + SP_CHUNK - 1) / SP_CHUNK;

    detect_kernel<<<(nsamp + 255) / 256, 256, 0, stream>>>((const int*)ei, flag, nsamp);
    splitA_kernel<<<gsplitA, 256, 0, stream>>>(ei, flag, gCnt, buf1, E, capS);
    splitB_kernel<<<dim3(gsplitBx, NS), 256, 0, stream>>>(gCnt, buf1, cnt2, buf2, capS,
                                                          cap2, NB);
    binB_kernel<<<NB, 256, 0, stream>>>(cnt2, buf2, cnt, n, cap2);
    scan_phaseA<<<nbA, SCAN_BS, 0, stream>>>(cnt, rowend, bsums, n);
    scan_phaseB<<<1, 128, 0, stream>>>(bsums, nbA);
    scan_phaseC<<<g256, 256, 0, stream>>>(rowend, bsums, n);
    dinv_kernel<<<g256, 256, 0, stream>>>(cnt, dinv, n);
    binC_kernel<<<NB, 256, 0, stream>>>(cnt2, buf2, rowend, cnt, colb, n, cap2);

    // layer 1: T(bf16) = x @ W1 ; Hb = relu(agg(T) + b1)
    gemm_k128<128, 8, 1><<<ggemm, 256, 0, stream>>>(x, W1, T, n);
    agg_relu_128_bf16<<<gagg, 256, 0, stream>>>((const unsigned short*)T, rowend, cnt,
                                                colb, dinv, b1, Hb, n, 1);
    // layer 2: T(bf16) = Hb @ W2 ; Hb = relu(agg(T) + b2)
    gemm_k128<128, 8, 1><<<ggemm, 256, 0, stream>>>(Hb, W2, T, n);
    agg_relu_128_bf16<<<gagg, 256, 0, stream>>>((const unsigned short*)T, rowend, cnt,
                                                colb, dinv, b2, Hb, n, 1);
    // layer 3: T(bf16) = Hb @ W3 ; out = log_softmax(agg(T) + b3)
    gemm_k128<64, 4, 1><<<ggemm, 256, 0, stream>>>(Hb, W3, T, n);
    agg_lsm_64_bf16<<<gagg, 256, 0, stream>>>((const unsigned short*)T, rowend, cnt,
                                              colb, dinv, b3, out, n);
}

// Round 6
// 440.186 us; speedup vs baseline: 1.6772x; 1.2071x over previous
//
#include <hip/hip_runtime.h>
#include <stdint.h>
#include <math.h>

#define FIN 128

typedef __attribute__((ext_vector_type(8))) short short8v;
typedef __attribute__((ext_vector_type(4))) float float4v;

// ---------------- bf16 helpers (manual, RNE) ----------------
__device__ __forceinline__ float2 bf2_to_f2(uint32_t u) {
    union { uint32_t i; float f; } a, b;
    a.i = (u & 0xFFFFu) << 16;
    b.i = u & 0xFFFF0000u;
    return make_float2(a.f, b.f);
}
__device__ __forceinline__ float bf_to_f(unsigned short u) {
    union { uint32_t i; float f; } a;
    a.i = ((uint32_t)u) << 16;
    return a.f;
}
__device__ __forceinline__ uint32_t f2_to_bf2(float x, float y) {
    union { float f; uint32_t i; } a, b;
    a.f = x; b.f = y;
    uint32_t ax = a.i + 0x7FFF + ((a.i >> 16) & 1);
    uint32_t by = b.i + 0x7FFF + ((b.i >> 16) & 1);
    return (ax >> 16) | (by & 0xFFFF0000u);
}
__device__ __forceinline__ unsigned short f_to_bf(float x) {
    union { float f; uint32_t i; } a;
    a.f = x;
    uint32_t u = a.i + 0x7FFF + ((a.i >> 16) & 1);
    return (unsigned short)(u >> 16);
}

// ---------------- edge dtype detection ----------------
__global__ __launch_bounds__(256) void detect_kernel(const int* __restrict__ ei32,
                                                     int* __restrict__ flag, int nsamp) {
    int i = blockIdx.x * 256 + threadIdx.x;
    if (i < nsamp) {
        if (ei32[2 * i + 1] != 0) atomicOr(flag, 1);
    }
}

__device__ __forceinline__ int edge_at(const void* ei, long long idx, int is32) {
    return is32 ? ((const int*)ei)[idx] : (int)((const long long*)ei)[idx];
}

// ---------------- Level-1 split: 16 super-bins (dst>>13) ----------------
#define SP_CHUNK 4096
__global__ __launch_bounds__(256) void splitA_kernel(const void* __restrict__ ei,
                                                     const int* __restrict__ flag,
                                                     int* __restrict__ gCnt,
                                                     uint2* __restrict__ buf1,
                                                     int E, int capS) {
    __shared__ int hist[16];
    __shared__ int gbase[16];
    int t = threadIdx.x;
    if (t < 16) hist[t] = 0;
    __syncthreads();
    int is32 = *flag;
    long long base = (long long)blockIdx.x * SP_CHUNK;
    uint32_t lrec[16], rs[16], rd[16];
#pragma unroll
    for (int j = 0; j < 16; ++j) {
        long long e = base + t + j * 256;
        if (e < E) {
            int s = edge_at(ei, e, is32);
            int d = edge_at(ei, (long long)E + e, is32);
            int b = d >> 13;
            int lofs = atomicAdd(&hist[b], 1);
            lrec[j] = ((uint32_t)lofs << 4) | (uint32_t)b;
            rs[j] = (uint32_t)s;
            rd[j] = (uint32_t)d;
        } else
            lrec[j] = 0xFFFFFFFFu;
    }
    __syncthreads();
    if (t < 16) gbase[t] = atomicAdd(&gCnt[t], hist[t]);
    __syncthreads();
#pragma unroll
    for (int j = 0; j < 16; ++j) {
        if (lrec[j] != 0xFFFFFFFFu) {
            int b = lrec[j] & 15;
            int pos = gbase[b] + (int)(lrec[j] >> 4);
            if (pos < capS) buf1[(size_t)b * capS + pos] = make_uint2(rs[j], rd[j]);
        }
    }
}

// ---------------- Level-2 split: 128 sub-bins of 64 nodes ----------------
__global__ __launch_bounds__(256) void splitB_kernel(const int* __restrict__ gCnt,
                                                     const uint2* __restrict__ buf1,
                                                     int* __restrict__ cnt2,
                                                     uint32_t* __restrict__ buf2,
                                                     int capS, int cap2, int NB) {
    __shared__ int hist[128];
    __shared__ int gbase[128];
    int t = threadIdx.x;
    int s = blockIdx.y;
    if (t < 128) hist[t] = 0;
    __syncthreads();
    int m = gCnt[s];
    if (m > capS) m = capS;
    long long base = (long long)blockIdx.x * SP_CHUNK;
    uint32_t lrec[16], r32[16];
#pragma unroll
    for (int j = 0; j < 16; ++j) {
        long long i = base + t + j * 256;
        if (i < m) {
            uint2 r = buf1[(size_t)s * capS + i];
            int d = (int)r.y;
            int sub = (d >> 6) & 127;
            int lofs = atomicAdd(&hist[sub], 1);
            lrec[j] = ((uint32_t)lofs << 7) | (uint32_t)sub;
            r32[j] = (r.x << 6) | (uint32_t)(d & 63);
        } else
            lrec[j] = 0xFFFFFFFFu;
    }
    __syncthreads();
    if (t < 128) {
        int g = s * 128 + t;
        gbase[t] = (g < NB) ? atomicAdd(&cnt2[g], hist[t]) : 0;
    }
    __syncthreads();
#pragma unroll
    for (int j = 0; j < 16; ++j) {
        if (lrec[j] != 0xFFFFFFFFu) {
            int sub = lrec[j] & 127;
            int pos = gbase[sub] + (int)(lrec[j] >> 7);
            if (pos < cap2) buf2[(size_t)(s * 128 + sub) * cap2 + pos] = r32[j];
        }
    }
}

// ---------------- per-node degree via LDS histogram ----------------
__global__ __launch_bounds__(256) void binB_kernel(const int* __restrict__ cnt2,
                                                   const uint32_t* __restrict__ buf2,
                                                   int* __restrict__ cnt, int n, int cap2) {
    __shared__ int h[64];
    int bin = blockIdx.x;
    int t = threadIdx.x;
    if (t < 64) h[t] = 0;
    __syncthreads();
    int m = cnt2[bin];
    if (m > cap2) m = cap2;
    const uint32_t* buf = buf2 + (size_t)bin * cap2;
    for (int i = t; i < m; i += 256) atomicAdd(&h[buf[i] & 63], 1);
    __syncthreads();
    if (t < 64) {
        int node = bin * 64 + t;
        if (node < n) cnt[node] = h[t];
    }
}

// ---------------- 3-phase scan (inclusive) ----------------
#define SCAN_BS 1024
__global__ __launch_bounds__(SCAN_BS) void scan_phaseA(const int* __restrict__ cnt,
                                                       int* __restrict__ incl,
                                                       int* __restrict__ bsums, int n) {
    __shared__ int sm[SCAN_BS];
    int gid = blockIdx.x * SCAN_BS + threadIdx.x;
    int v = (gid < n) ? cnt[gid] : 0;
    sm[threadIdx.x] = v;
    __syncthreads();
    for (int off = 1; off < SCAN_BS; off <<= 1) {
        int t = 0;
        if ((int)threadIdx.x >= off) t = sm[threadIdx.x - off];
        __syncthreads();
        sm[threadIdx.x] += t;
        __syncthreads();
    }
    if (gid < n) incl[gid] = sm[threadIdx.x];
    if (threadIdx.x == SCAN_BS - 1) bsums[blockIdx.x] = sm[threadIdx.x];
}

__global__ __launch_bounds__(128) void scan_phaseB(int* __restrict__ bsums, int nb) {
    __shared__ int sm[128];
    int v = ((int)threadIdx.x < nb) ? bsums[threadIdx.x] : 0;
    sm[threadIdx.x] = v;
    __syncthreads();
    for (int off = 1; off < 128; off <<= 1) {
        int t = 0;
        if ((int)threadIdx.x >= off) t = sm[threadIdx.x - off];
        __syncthreads();
        sm[threadIdx.x] += t;
        __syncthreads();
    }
    if ((int)threadIdx.x < nb)
        bsums[threadIdx.x] = (threadIdx.x == 0) ? 0 : sm[threadIdx.x - 1];
}

__global__ __launch_bounds__(256) void scan_phaseC(int* __restrict__ incl,
                                                   const int* __restrict__ bsums, int n) {
    int gid = blockIdx.x * 256 + threadIdx.x;
    if (gid < n) incl[gid] += bsums[gid >> 10];
}

// ---------------- dinv = rsqrt(deg) ----------------
__global__ __launch_bounds__(256) void dinv_kernel(const int* __restrict__ cnt,
                                                   float* __restrict__ dinv, int n) {
    int i = blockIdx.x * 256 + threadIdx.x;
    if (i < n) dinv[i] = rsqrtf((float)cnt[i] + 1.0f);
}

// ---------------- scatter bin records into CSR ----------------
__global__ __launch_bounds__(256) void binC_kernel(const int* __restrict__ cnt2,
                                                   const uint32_t* __restrict__ buf2,
                                                   const int* __restrict__ rowend,
                                                   const int* __restrict__ cnt,
                                                   int* __restrict__ col, int n, int cap2) {
    __shared__ int rowst[64];
    __shared__ int cur[64];
    int bin = blockIdx.x;
    int t = threadIdx.x;
    if (t < 64) {
        cur[t] = 0;
        int node = bin * 64 + t;
        rowst[t] = (node < n) ? rowend[node] - cnt[node] : 0;
    }
    __syncthreads();
    int m = cnt2[bin];
    if (m > cap2) m = cap2;
    const uint32_t* buf = buf2 + (size_t)bin * cap2;
    for (int i = t; i < m; i += 256) {
        uint32_t rec = buf[i];
        int d6 = rec & 63;
        int off = atomicAdd(&cur[d6], 1);
        col[rowst[d6] + off] = (int)(rec >> 6);
    }
}

// ---------------- W -> fragment-ordered bf16 (all 3 weights, one kernel) ----------
// Wf[(f*64+l)*8 + j] = W[ks*32 + (l>>4)*8 + j][ct*16 + (l&15)], f = ct*4 + ks
__global__ __launch_bounds__(256) void wconv_all(const float* __restrict__ W1,
                                                 const float* __restrict__ W2,
                                                 const float* __restrict__ W3,
                                                 unsigned short* __restrict__ Wf1,
                                                 unsigned short* __restrict__ Wf2,
                                                 unsigned short* __restrict__ Wf3) {
    int idx = blockIdx.x * 256 + threadIdx.x;
    const float* W;
    unsigned short* Wf;
    int NCOL, base;
    if (idx < 2048)      { W = W1; Wf = Wf1; NCOL = 128; base = idx; }
    else if (idx < 4096) { W = W2; Wf = Wf2; NCOL = 128; base = idx - 2048; }
    else if (idx < 5120) { W = W3; Wf = Wf3; NCOL = 64;  base = idx - 4096; }
    else return;
    int f = base >> 6, l = base & 63;
    int ct = f >> 2, ks = f & 3;
    int nn = ct * 16 + (l & 15);
    int k0 = ks * 32 + (l >> 4) * 8;
    uint32_t pk[4];
#pragma unroll
    for (int j = 0; j < 4; ++j) {
        float a = W[(size_t)(k0 + 2 * j) * NCOL + nn];
        float b = W[(size_t)(k0 + 2 * j + 1) * NCOL + nn];
        pk[j] = f2_to_bf2(a, b);
    }
    uint4 v = make_uint4(pk[0], pk[1], pk[2], pk[3]);
    ((uint4*)Wf)[base] = v;
}

// ---------------- MFMA GEMM: C(bf16)[n x NCOL] = A[n x 128] @ W[128 x NCOL] ------
// 4 waves/block, wave = 16 rows x NCOL cols. Wf staged to LDS in frag order
// (b-reads are the canonical lane*16B conflict-free ds_read_b128 pattern).
// A_FP32: layer-1 input is fp32 x, converted in-register.
template <int NCOL, int A_FP32>
__global__ __launch_bounds__(256) void gemm_mfma(const void* __restrict__ Av,
                                                 const unsigned short* __restrict__ Wf,
                                                 unsigned short* __restrict__ C, int n) {
    __shared__ unsigned short lds[NCOL * 128];
    const int t = threadIdx.x;
    // stage Wf: NCOL*128 bf16 = NCOL*16 uint4s  (R5 bug: was NCOL*8 -> half poison)
    for (int i = t; i < NCOL * 16; i += 256)
        ((uint4*)lds)[i] = ((const uint4*)Wf)[i];
    __syncthreads();

    const int wave = t >> 6, lane = t & 63;
    const int row0 = blockIdx.x * 64 + wave * 16;
    const int m = lane & 15, quad = lane >> 4;
    int arow = row0 + m;
    if (arow >= n) arow = n - 1;

    short8v a[4];
    if (A_FP32) {
        const float* A = (const float*)Av;
#pragma unroll
        for (int ks = 0; ks < 4; ++ks) {
            float4 lo = *(const float4*)(A + (size_t)arow * 128 + ks * 32 + quad * 8);
            float4 hi = *(const float4*)(A + (size_t)arow * 128 + ks * 32 + quad * 8 + 4);
            union { short8v v; uint32_t u[4]; } pk;
            pk.u[0] = f2_to_bf2(lo.x, lo.y);
            pk.u[1] = f2_to_bf2(lo.z, lo.w);
            pk.u[2] = f2_to_bf2(hi.x, hi.y);
            pk.u[3] = f2_to_bf2(hi.z, hi.w);
            a[ks] = pk.v;
        }
    } else {
        const unsigned short* A = (const unsigned short*)Av;
#pragma unroll
        for (int ks = 0; ks < 4; ++ks)
            a[ks] = *(const short8v*)(A + (size_t)arow * 128 + ks * 32 + quad * 8);
    }

    const int cr0 = row0 + quad * 4;
#pragma unroll
    for (int ct = 0; ct < NCOL / 16; ++ct) {
        float4v acc = {0.0f, 0.0f, 0.0f, 0.0f};
#pragma unroll
        for (int ks = 0; ks < 4; ++ks) {
            int f = ct * 4 + ks;
            short8v b = *(const short8v*)(lds + ((size_t)(f * 64 + lane)) * 8);
            acc = __builtin_amdgcn_mfma_f32_16x16x32_bf16(a[ks], b, acc, 0, 0, 0);
        }
#pragma unroll
        for (int r = 0; r < 4; ++r) {
            int gr = cr0 + r;
            if (gr < n) C[(size_t)gr * NCOL + ct * 16 + m] = f_to_bf(acc[r]);
        }
    }
}

// ---------------- aggregation, width 128, bf16 T -> bf16 out ----------------
__global__ __launch_bounds__(256) void agg_relu_128_bf16(
        const unsigned short* __restrict__ T, const int* __restrict__ rowend,
        const int* __restrict__ cnt, const int* __restrict__ col,
        const float* __restrict__ dinv, const float* __restrict__ bias,
        uint32_t* __restrict__ out, int n, int do_relu) {
    int node = blockIdx.x * 4 + (threadIdx.x >> 6);
    if (node >= n) return;
    int lane = threadIdx.x & 63;
    int end = rowend[node];
    int start = end - cnt[node];
    float di = dinv[node];
    float2 sv = bf2_to_f2(((const uint32_t*)(T + (size_t)node * 128))[lane]);
    float acc0 = sv.x * di;
    float acc1 = sv.y * di;
    int p = start;
    for (; p + 8 <= end; p += 8) {
        int s0 = col[p + 0], s1 = col[p + 1], s2 = col[p + 2], s3 = col[p + 3];
        int s4 = col[p + 4], s5 = col[p + 5], s6 = col[p + 6], s7 = col[p + 7];
        float w0 = dinv[s0], w1 = dinv[s1], w2 = dinv[s2], w3 = dinv[s3];
        float w4 = dinv[s4], w5 = dinv[s5], w6 = dinv[s6], w7 = dinv[s7];
        uint32_t u0 = ((const uint32_t*)(T + (size_t)s0 * 128))[lane];
        uint32_t u1 = ((const uint32_t*)(T + (size_t)s1 * 128))[lane];
        uint32_t u2 = ((const uint32_t*)(T + (size_t)s2 * 128))[lane];
        uint32_t u3 = ((const uint32_t*)(T + (size_t)s3 * 128))[lane];
        uint32_t u4 = ((const uint32_t*)(T + (size_t)s4 * 128))[lane];
        uint32_t u5 = ((const uint32_t*)(T + (size_t)s5 * 128))[lane];
        uint32_t u6 = ((const uint32_t*)(T + (size_t)s6 * 128))[lane];
        uint32_t u7 = ((const uint32_t*)(T + (size_t)s7 * 128))[lane];
        float2 v;
        v = bf2_to_f2(u0); acc0 += w0 * v.x; acc1 += w0 * v.y;
        v = bf2_to_f2(u1); acc0 += w1 * v.x; acc1 += w1 * v.y;
        v = bf2_to_f2(u2); acc0 += w2 * v.x; acc1 += w2 * v.y;
        v = bf2_to_f2(u3); acc0 += w3 * v.x; acc1 += w3 * v.y;
        v = bf2_to_f2(u4); acc0 += w4 * v.x; acc1 += w4 * v.y;
        v = bf2_to_f2(u5); acc0 += w5 * v.x; acc1 += w5 * v.y;
        v = bf2_to_f2(u6); acc0 += w6 * v.x; acc1 += w6 * v.y;
        v = bf2_to_f2(u7); acc0 += w7 * v.x; acc1 += w7 * v.y;
    }
    for (; p < end; ++p) {
        int s = col[p];
        float w = dinv[s];
        float2 v = bf2_to_f2(((const uint32_t*)(T + (size_t)s * 128))[lane]);
        acc0 += w * v.x;
        acc1 += w * v.y;
    }
    float2 b2 = ((const float2*)bias)[lane];
    float v0 = di * acc0 + b2.x;
    float v1 = di * acc1 + b2.y;
    if (do_relu) { v0 = fmaxf(v0, 0.0f); v1 = fmaxf(v1, 0.0f); }
    out[(size_t)node * 64 + lane] = f2_to_bf2(v0, v1);
}

// ---------------- aggregation width 64 (bf16 T) + bias + log_softmax ----------------
__global__ __launch_bounds__(256) void agg_lsm_64_bf16(
        const unsigned short* __restrict__ T, const int* __restrict__ rowend,
        const int* __restrict__ cnt, const int* __restrict__ col,
        const float* __restrict__ dinv, const float* __restrict__ bias,
        float* __restrict__ out, int n) {
    int node = blockIdx.x * 4 + (threadIdx.x >> 6);
    if (node >= n) return;
    int lane = threadIdx.x & 63;
    int end = rowend[node];
    int start = end - cnt[node];
    float di = dinv[node];
    float acc = bf_to_f(T[(size_t)node * 64 + lane]) * di;
    int p = start;
    for (; p + 8 <= end; p += 8) {
        int s0 = col[p + 0], s1 = col[p + 1], s2 = col[p + 2], s3 = col[p + 3];
        int s4 = col[p + 4], s5 = col[p + 5], s6 = col[p + 6], s7 = col[p + 7];
        float w0 = dinv[s0], w1 = dinv[s1], w2 = dinv[s2], w3 = dinv[s3];
        float w4 = dinv[s4], w5 = dinv[s5], w6 = dinv[s6], w7 = dinv[s7];
        unsigned short u0 = T[(size_t)s0 * 64 + lane];
        unsigned short u1 = T[(size_t)s1 * 64 + lane];
        unsigned short u2 = T[(size_t)s2 * 64 + lane];
        unsigned short u3 = T[(size_t)s3 * 64 + lane];
        unsigned short u4 = T[(size_t)s4 * 64 + lane];
        unsigned short u5 = T[(size_t)s5 * 64 + lane];
        unsigned short u6 = T[(size_t)s6 * 64 + lane];
        unsigned short u7 = T[(size_t)s7 * 64 + lane];
        acc += w0 * bf_to_f(u0) + w1 * bf_to_f(u1) + w2 * bf_to_f(u2) + w3 * bf_to_f(u3);
        acc += w4 * bf_to_f(u4) + w5 * bf_to_f(u5) + w6 * bf_to_f(u6) + w7 * bf_to_f(u7);
    }
    for (; p < end; ++p) {
        int s = col[p];
        acc += dinv[s] * bf_to_f(T[(size_t)s * 64 + lane]);
    }
    float r = di * acc + bias[lane];
    float m = r;
    for (int o = 32; o > 0; o >>= 1) m = fmaxf(m, __shfl_xor(m, o, 64));
    float e = expf(r - m);
    float ssum = e;
    for (int o = 32; o > 0; o >>= 1) ssum += __shfl_xor(ssum, o, 64);
    out[(size_t)node * 64 + lane] = r - m - logf(ssum);
}

// ---------------- launcher ----------------
extern "C" void kernel_launch(void* const* d_in, const int* in_sizes, int n_in,
                              void* d_out, int out_size, void* d_ws, size_t ws_size,
                              hipStream_t stream) {
    const float* x  = (const float*)d_in[0];
    const void*  ei = d_in[1];
    const float* W1 = (const float*)d_in[2];
    const float* b1 = (const float*)d_in[3];
    const float* W2 = (const float*)d_in[4];
    const float* b2 = (const float*)d_in[5];
    const float* W3 = (const float*)d_in[6];
    const float* b3 = (const float*)d_in[7];
    float* out = (float*)d_out;

    const int n = in_sizes[0] / FIN;       // 100000
    const int E = in_sizes[1] / 2;         // 1600000

    char* p = (char*)d_ws;
    auto carve = [&](size_t bytes) {
        char* q = p;
        p += (bytes + 255) & ~(size_t)255;
        return q;
    };
    int*   cnt    = (int*)carve((size_t)n * 4);
    int*   flag   = (int*)carve(256);
    int*   rowend = (int*)carve((size_t)n * 4);
    int*   bsums  = (int*)carve(1024 * 4);
    float* dinv   = (float*)carve((size_t)n * 4);
    int*   colb   = (int*)carve((size_t)E * 4);
    size_t Tbytes = (size_t)n * 128 * 2;   // bf16 n x 128 (also aliased by split bufs)
    void*  T      = (void*)carve(Tbytes);
    unsigned short* Hb = (unsigned short*)carve((size_t)n * 128 * 2);  // bf16
    unsigned short* Wf1 = (unsigned short*)carve(128 * 128 * 2);
    unsigned short* Wf2 = (unsigned short*)carve(128 * 128 * 2);
    unsigned short* Wf3 = (unsigned short*)carve(128 * 64 * 2);

    const int NB = (n + 63) / 64;          // 64-node bins
    const int NS = (n + 8191) / 8192;      // 8192-node super-bins
    int*  gCnt = (int*)carve((size_t)16 * 4);
    int*  cnt2 = (int*)carve((size_t)NB * 4);

    long long meanS = (long long)E * 8192 / n;
    int capS = (int)(meanS + 8 * (long long)sqrt((double)meanS) + 1024);
    capS = (capS + 15) & ~15;
    long long mean2 = (long long)E * 64 / n;
    int cap2 = (int)(mean2 + 8 * (long long)sqrt((double)mean2) + 64);
    cap2 = (cap2 + 15) & ~15;
    size_t buf1B = ((size_t)NS * capS * 8 + 255) & ~(size_t)255;
    uint2*    buf1 = (uint2*)T;
    uint32_t* buf2 = (uint32_t*)((char*)T + buf1B);
    size_t avail2 = (Tbytes > buf1B) ? (Tbytes - buf1B) : 0;
    size_t maxc2 = avail2 / ((size_t)NB * 4);
    if ((size_t)cap2 > maxc2) cap2 = (int)maxc2;

    hipMemsetAsync(flag, 0, 4, stream);
    hipMemsetAsync(gCnt, 0, 16 * 4, stream);
    hipMemsetAsync(cnt2, 0, (size_t)NB * 4, stream);

    const int g256 = (n + 255) / 256;
    const int nbA = (n + SCAN_BS - 1) / SCAN_BS;
    const int gagg = (n + 3) / 4;
    const int ggemm = (n + 63) / 64;
    const int nsamp = E < 65536 ? E : 65536;
    const int gsplitA = (E + SP_CHUNK - 1) / SP_CHUNK;
    const int gsplitBx = (capS + SP_CHUNK - 1) / SP_CHUNK;

    detect_kernel<<<(nsamp + 255) / 256, 256, 0, stream>>>((const int*)ei, flag, nsamp);
    splitA_kernel<<<gsplitA, 256, 0, stream>>>(ei, flag, gCnt, buf1, E, capS);
    splitB_kernel<<<dim3(gsplitBx, NS), 256, 0, stream>>>(gCnt, buf1, cnt2, buf2, capS,
                                                          cap2, NB);
    binB_kernel<<<NB, 256, 0, stream>>>(cnt2, buf2, cnt, n, cap2);
    scan_phaseA<<<nbA, SCAN_BS, 0, stream>>>(cnt, rowend, bsums, n);
    scan_phaseB<<<1, 128, 0, stream>>>(bsums, nbA);
    scan_phaseC<<<g256, 256, 0, stream>>>(rowend, bsums, n);
    dinv_kernel<<<g256, 256, 0, stream>>>(cnt, dinv, n);
    binC_kernel<<<NB, 256, 0, stream>>>(cnt2, buf2, rowend, cnt, colb, n, cap2);
    wconv_all<<<20, 256, 0, stream>>>(W1, W2, W3, Wf1, Wf2, Wf3);

    // layer 1: T(bf16) = x @ W1 (MFMA) ; Hb(bf16) = relu(agg(T) + b1)
    gemm_mfma<128, 1><<<ggemm, 256, 0, stream>>>(x, Wf1, (unsigned short*)T, n);
    agg_relu_128_bf16<<<gagg, 256, 0, stream>>>((const unsigned short*)T, rowend, cnt,
                                                colb, dinv, b1, (uint32_t*)Hb, n, 1);
    // layer 2
    gemm_mfma<128, 0><<<ggemm, 256, 0, stream>>>(Hb, Wf2, (unsigned short*)T, n);
    agg_relu_128_bf16<<<gagg, 256, 0, stream>>>((const unsigned short*)T, rowend, cnt,
                                                colb, dinv, b2, (uint32_t*)Hb, n, 1);
    // layer 3
    gemm_mfma<64, 0><<<ggemm, 256, 0, stream>>>(Hb, Wf3, (unsigned short*)T, n);
    agg_lsm_64_bf16<<<gagg, 256, 0, stream>>>((const unsigned short*)T, rowend, cnt,
                                              colb, dinv, b3, out, n);
}

// Round 7
// 391.603 us; speedup vs baseline: 1.8853x; 1.1241x over previous
//
#include <hip/hip_runtime.h>
#include <stdint.h>
#include <math.h>

#define FIN 128

typedef __attribute__((ext_vector_type(8))) short short8v;
typedef __attribute__((ext_vector_type(4))) float float4v;

// ---------------- bf16 helpers (manual, RNE) ----------------
__device__ __forceinline__ float2 bf2_to_f2(uint32_t u) {
    union { uint32_t i; float f; } a, b;
    a.i = (u & 0xFFFFu) << 16;
    b.i = u & 0xFFFF0000u;
    return make_float2(a.f, b.f);
}
__device__ __forceinline__ float bf_to_f(unsigned short u) {
    union { uint32_t i; float f; } a;
    a.i = ((uint32_t)u) << 16;
    return a.f;
}
__device__ __forceinline__ uint32_t f2_to_bf2(float x, float y) {
    union { float f; uint32_t i; } a, b;
    a.f = x; b.f = y;
    uint32_t ax = a.i + 0x7FFF + ((a.i >> 16) & 1);
    uint32_t by = b.i + 0x7FFF + ((b.i >> 16) & 1);
    return (ax >> 16) | (by & 0xFFFF0000u);
}
__device__ __forceinline__ unsigned short f_to_bf(float x) {
    union { float f; uint32_t i; } a;
    a.f = x;
    uint32_t u = a.i + 0x7FFF + ((a.i >> 16) & 1);
    return (unsigned short)(u >> 16);
}
// add 8 bf16 (uint4) into acc[8]
__device__ __forceinline__ void acc8_add(float* acc, uint4 v) {
    float2 f;
    f = bf2_to_f2(v.x); acc[0] += f.x; acc[1] += f.y;
    f = bf2_to_f2(v.y); acc[2] += f.x; acc[3] += f.y;
    f = bf2_to_f2(v.z); acc[4] += f.x; acc[5] += f.y;
    f = bf2_to_f2(v.w); acc[6] += f.x; acc[7] += f.y;
}

// ---------------- edge dtype detection ----------------
__global__ __launch_bounds__(256) void detect_kernel(const int* __restrict__ ei32,
                                                     int* __restrict__ flag, int nsamp) {
    int i = blockIdx.x * 256 + threadIdx.x;
    if (i < nsamp) {
        if (ei32[2 * i + 1] != 0) atomicOr(flag, 1);
    }
}

__device__ __forceinline__ int edge_at(const void* ei, long long idx, int is32) {
    return is32 ? ((const int*)ei)[idx] : (int)((const long long*)ei)[idx];
}

// ---------------- Level-1 split: 16 super-bins (dst>>13) ----------------
#define SP_CHUNK 4096
__global__ __launch_bounds__(256) void splitA_kernel(const void* __restrict__ ei,
                                                     const int* __restrict__ flag,
                                                     int* __restrict__ gCnt,
                                                     uint2* __restrict__ buf1,
                                                     int E, int capS) {
    __shared__ int hist[16];
    __shared__ int gbase[16];
    int t = threadIdx.x;
    if (t < 16) hist[t] = 0;
    __syncthreads();
    int is32 = *flag;
    long long base = (long long)blockIdx.x * SP_CHUNK;
    uint32_t lrec[16], rs[16], rd[16];
#pragma unroll
    for (int j = 0; j < 16; ++j) {
        long long e = base + t + j * 256;
        if (e < E) {
            int s = edge_at(ei, e, is32);
            int d = edge_at(ei, (long long)E + e, is32);
            int b = d >> 13;
            int lofs = atomicAdd(&hist[b], 1);
            lrec[j] = ((uint32_t)lofs << 4) | (uint32_t)b;
            rs[j] = (uint32_t)s;
            rd[j] = (uint32_t)d;
        } else
            lrec[j] = 0xFFFFFFFFu;
    }
    __syncthreads();
    if (t < 16) gbase[t] = atomicAdd(&gCnt[t], hist[t]);
    __syncthreads();
#pragma unroll
    for (int j = 0; j < 16; ++j) {
        if (lrec[j] != 0xFFFFFFFFu) {
            int b = lrec[j] & 15;
            int pos = gbase[b] + (int)(lrec[j] >> 4);
            if (pos < capS) buf1[(size_t)b * capS + pos] = make_uint2(rs[j], rd[j]);
        }
    }
}

// ---------------- Level-2 split: 128 sub-bins of 64 nodes ----------------
__global__ __launch_bounds__(256) void splitB_kernel(const int* __restrict__ gCnt,
                                                     const uint2* __restrict__ buf1,
                                                     int* __restrict__ cnt2,
                                                     uint32_t* __restrict__ buf2,
                                                     int capS, int cap2, int NB) {
    __shared__ int hist[128];
    __shared__ int gbase[128];
    int t = threadIdx.x;
    int s = blockIdx.y;
    if (t < 128) hist[t] = 0;
    __syncthreads();
    int m = gCnt[s];
    if (m > capS) m = capS;
    long long base = (long long)blockIdx.x * SP_CHUNK;
    uint32_t lrec[16], r32[16];
#pragma unroll
    for (int j = 0; j < 16; ++j) {
        long long i = base + t + j * 256;
        if (i < m) {
            uint2 r = buf1[(size_t)s * capS + i];
            int d = (int)r.y;
            int sub = (d >> 6) & 127;
            int lofs = atomicAdd(&hist[sub], 1);
            lrec[j] = ((uint32_t)lofs << 7) | (uint32_t)sub;
            r32[j] = (r.x << 6) | (uint32_t)(d & 63);
        } else
            lrec[j] = 0xFFFFFFFFu;
    }
    __syncthreads();
    if (t < 128) {
        int g = s * 128 + t;
        gbase[t] = (g < NB) ? atomicAdd(&cnt2[g], hist[t]) : 0;
    }
    __syncthreads();
#pragma unroll
    for (int j = 0; j < 16; ++j) {
        if (lrec[j] != 0xFFFFFFFFu) {
            int sub = lrec[j] & 127;
            int pos = gbase[sub] + (int)(lrec[j] >> 7);
            if (pos < cap2) buf2[(size_t)(s * 128 + sub) * cap2 + pos] = r32[j];
        }
    }
}

// ---------------- per-node degree via LDS histogram ----------------
__global__ __launch_bounds__(256) void binB_kernel(const int* __restrict__ cnt2,
                                                   const uint32_t* __restrict__ buf2,
                                                   int* __restrict__ cnt, int n, int cap2) {
    __shared__ int h[64];
    int bin = blockIdx.x;
    int t = threadIdx.x;
    if (t < 64) h[t] = 0;
    __syncthreads();
    int m = cnt2[bin];
    if (m > cap2) m = cap2;
    const uint32_t* buf = buf2 + (size_t)bin * cap2;
    for (int i = t; i < m; i += 256) atomicAdd(&h[buf[i] & 63], 1);
    __syncthreads();
    if (t < 64) {
        int node = bin * 64 + t;
        if (node < n) cnt[node] = h[t];
    }
}

// ---------------- 3-phase scan (inclusive) ----------------
#define SCAN_BS 1024
__global__ __launch_bounds__(SCAN_BS) void scan_phaseA(const int* __restrict__ cnt,
                                                       int* __restrict__ incl,
                                                       int* __restrict__ bsums, int n) {
    __shared__ int sm[SCAN_BS];
    int gid = blockIdx.x * SCAN_BS + threadIdx.x;
    int v = (gid < n) ? cnt[gid] : 0;
    sm[threadIdx.x] = v;
    __syncthreads();
    for (int off = 1; off < SCAN_BS; off <<= 1) {
        int t = 0;
        if ((int)threadIdx.x >= off) t = sm[threadIdx.x - off];
        __syncthreads();
        sm[threadIdx.x] += t;
        __syncthreads();
    }
    if (gid < n) incl[gid] = sm[threadIdx.x];
    if (threadIdx.x == SCAN_BS - 1) bsums[blockIdx.x] = sm[threadIdx.x];
}

__global__ __launch_bounds__(128) void scan_phaseB(int* __restrict__ bsums, int nb) {
    __shared__ int sm[128];
    int v = ((int)threadIdx.x < nb) ? bsums[threadIdx.x] : 0;
    sm[threadIdx.x] = v;
    __syncthreads();
    for (int off = 1; off < 128; off <<= 1) {
        int t = 0;
        if ((int)threadIdx.x >= off) t = sm[threadIdx.x - off];
        __syncthreads();
        sm[threadIdx.x] += t;
        __syncthreads();
    }
    if ((int)threadIdx.x < nb)
        bsums[threadIdx.x] = (threadIdx.x == 0) ? 0 : sm[threadIdx.x - 1];
}

__global__ __launch_bounds__(256) void scan_phaseC(int* __restrict__ incl,
                                                   const int* __restrict__ bsums, int n) {
    int gid = blockIdx.x * 256 + threadIdx.x;
    if (gid < n) incl[gid] += bsums[gid >> 10];
}

// ---------------- dinv = rsqrt(deg) ----------------
__global__ __launch_bounds__(256) void dinv_kernel(const int* __restrict__ cnt,
                                                   float* __restrict__ dinv, int n) {
    int i = blockIdx.x * 256 + threadIdx.x;
    if (i < n) dinv[i] = rsqrtf((float)cnt[i] + 1.0f);
}

// ---------------- scatter bin records into CSR ----------------
__global__ __launch_bounds__(256) void binC_kernel(const int* __restrict__ cnt2,
                                                   const uint32_t* __restrict__ buf2,
                                                   const int* __restrict__ rowend,
                                                   const int* __restrict__ cnt,
                                                   int* __restrict__ col, int n, int cap2) {
    __shared__ int rowst[64];
    __shared__ int cur[64];
    int bin = blockIdx.x;
    int t = threadIdx.x;
    if (t < 64) {
        cur[t] = 0;
        int node = bin * 64 + t;
        rowst[t] = (node < n) ? rowend[node] - cnt[node] : 0;
    }
    __syncthreads();
    int m = cnt2[bin];
    if (m > cap2) m = cap2;
    const uint32_t* buf = buf2 + (size_t)bin * cap2;
    for (int i = t; i < m; i += 256) {
        uint32_t rec = buf[i];
        int d6 = rec & 63;
        int off = atomicAdd(&cur[d6], 1);
        col[rowst[d6] + off] = (int)(rec >> 6);
    }
}

// ---------------- W -> fragment-ordered bf16 ----------------
__global__ __launch_bounds__(256) void wconv_all(const float* __restrict__ W1,
                                                 const float* __restrict__ W2,
                                                 const float* __restrict__ W3,
                                                 unsigned short* __restrict__ Wf1,
                                                 unsigned short* __restrict__ Wf2,
                                                 unsigned short* __restrict__ Wf3) {
    int idx = blockIdx.x * 256 + threadIdx.x;
    const float* W;
    unsigned short* Wf;
    int NCOL, base;
    if (idx < 2048)      { W = W1; Wf = Wf1; NCOL = 128; base = idx; }
    else if (idx < 4096) { W = W2; Wf = Wf2; NCOL = 128; base = idx - 2048; }
    else if (idx < 5120) { W = W3; Wf = Wf3; NCOL = 64;  base = idx - 4096; }
    else return;
    int f = base >> 6, l = base & 63;
    int ct = f >> 2, ks = f & 3;
    int nn = ct * 16 + (l & 15);
    int k0 = ks * 32 + (l >> 4) * 8;
    uint32_t pk[4];
#pragma unroll
    for (int j = 0; j < 4; ++j) {
        float a = W[(size_t)(k0 + 2 * j) * NCOL + nn];
        float b = W[(size_t)(k0 + 2 * j + 1) * NCOL + nn];
        pk[j] = f2_to_bf2(a, b);
    }
    uint4 v = make_uint4(pk[0], pk[1], pk[2], pk[3]);
    ((uint4*)Wf)[base] = v;
}

// ---------------- MFMA GEMM + dinv row-scale epilogue ----------------
// C(bf16)[gr] = dinv[gr] * (A[gr] @ W). A_FP32: layer-1 fp32 input.
template <int NCOL, int A_FP32>
__global__ __launch_bounds__(256) void gemm_mfma(const void* __restrict__ Av,
                                                 const unsigned short* __restrict__ Wf,
                                                 const float* __restrict__ dinv,
                                                 unsigned short* __restrict__ C, int n) {
    __shared__ unsigned short lds[NCOL * 128];
    const int t = threadIdx.x;
    for (int i = t; i < NCOL * 16; i += 256)
        ((uint4*)lds)[i] = ((const uint4*)Wf)[i];
    __syncthreads();

    const int wave = t >> 6, lane = t & 63;
    const int row0 = blockIdx.x * 64 + wave * 16;
    const int m = lane & 15, quad = lane >> 4;
    int arow = row0 + m;
    if (arow >= n) arow = n - 1;

    short8v a[4];
    if (A_FP32) {
        const float* A = (const float*)Av;
#pragma unroll
        for (int ks = 0; ks < 4; ++ks) {
            float4 lo = *(const float4*)(A + (size_t)arow * 128 + ks * 32 + quad * 8);
            float4 hi = *(const float4*)(A + (size_t)arow * 128 + ks * 32 + quad * 8 + 4);
            union { short8v v; uint32_t u[4]; } pk;
            pk.u[0] = f2_to_bf2(lo.x, lo.y);
            pk.u[1] = f2_to_bf2(lo.z, lo.w);
            pk.u[2] = f2_to_bf2(hi.x, hi.y);
            pk.u[3] = f2_to_bf2(hi.z, hi.w);
            a[ks] = pk.v;
        }
    } else {
        const unsigned short* A = (const unsigned short*)Av;
#pragma unroll
        for (int ks = 0; ks < 4; ++ks)
            a[ks] = *(const short8v*)(A + (size_t)arow * 128 + ks * 32 + quad * 8);
    }

    const int cr0 = row0 + quad * 4;
    float ds[4];
#pragma unroll
    for (int r = 0; r < 4; ++r) {
        int gr = cr0 + r;
        ds[r] = (gr < n) ? dinv[gr] : 0.0f;
    }
#pragma unroll
    for (int ct = 0; ct < NCOL / 16; ++ct) {
        float4v acc = {0.0f, 0.0f, 0.0f, 0.0f};
#pragma unroll
        for (int ks = 0; ks < 4; ++ks) {
            int f = ct * 4 + ks;
            short8v b = *(const short8v*)(lds + ((size_t)(f * 64 + lane)) * 8);
            acc = __builtin_amdgcn_mfma_f32_16x16x32_bf16(a[ks], b, acc, 0, 0, 0);
        }
#pragma unroll
        for (int r = 0; r < 4; ++r) {
            int gr = cr0 + r;
            if (gr < n) C[(size_t)gr * NCOL + ct * 16 + m] = f_to_bf(acc[r] * ds[r]);
        }
    }
}

// ---------------- wide aggregation, 128 feats: T' rows pre-scaled by dinv ----------
// wave = 1 node; lane j=lane&15 covers feature octet j (16B), g=lane>>4 is edge slot;
// one wave gather instruction fetches 4 edges' rows (1KB). out bf16.
__global__ __launch_bounds__(256) void agg_relu_128_w(
        const unsigned short* __restrict__ T, const int* __restrict__ rowend,
        const int* __restrict__ cnt, const int* __restrict__ col,
        const float* __restrict__ dinv, const float* __restrict__ bias,
        uint32_t* __restrict__ out, int n, int do_relu) {
    int node = blockIdx.x * 4 + (threadIdx.x >> 6);
    if (node >= n) return;
    int lane = threadIdx.x & 63;
    int j = lane & 15, g = lane >> 4;
    int end = rowend[node];
    int start = end - cnt[node];
    float di = dinv[node];

    float acc[8];
#pragma unroll
    for (int k = 0; k < 8; ++k) acc[k] = 0.0f;
    // self-loop: T'[node], loaded by group 0 only
    if (g == 0) {
        uint4 v = *(const uint4*)(T + (size_t)node * 128 + j * 8);
        acc8_add(acc, v);
    }
    int p = start;
    for (; p + 16 <= end; p += 16) {
        int s0 = col[p + g], s1 = col[p + 4 + g];
        int s2 = col[p + 8 + g], s3 = col[p + 12 + g];
        uint4 v0 = *(const uint4*)(T + (size_t)s0 * 128 + j * 8);
        uint4 v1 = *(const uint4*)(T + (size_t)s1 * 128 + j * 8);
        uint4 v2 = *(const uint4*)(T + (size_t)s2 * 128 + j * 8);
        uint4 v3 = *(const uint4*)(T + (size_t)s3 * 128 + j * 8);
        acc8_add(acc, v0); acc8_add(acc, v1);
        acc8_add(acc, v2); acc8_add(acc, v3);
    }
    for (; p < end; p += 4) {
        int e = p + g;
        if (e < end) {
            int s = col[e];
            uint4 v = *(const uint4*)(T + (size_t)s * 128 + j * 8);
            acc8_add(acc, v);
        }
    }
    // reduce across the 4 edge groups
#pragma unroll
    for (int k = 0; k < 8; ++k) {
        acc[k] += __shfl_xor(acc[k], 16, 64);
        acc[k] += __shfl_xor(acc[k], 32, 64);
    }
    if (g == 0) {
        const float4* b4 = (const float4*)bias;
        float4 ba = b4[j * 2], bb = b4[j * 2 + 1];
        float r[8];
        r[0] = di * acc[0] + ba.x; r[1] = di * acc[1] + ba.y;
        r[2] = di * acc[2] + ba.z; r[3] = di * acc[3] + ba.w;
        r[4] = di * acc[4] + bb.x; r[5] = di * acc[5] + bb.y;
        r[6] = di * acc[6] + bb.z; r[7] = di * acc[7] + bb.w;
        if (do_relu)
#pragma unroll
            for (int k = 0; k < 8; ++k) r[k] = fmaxf(r[k], 0.0f);
        uint4 o;
        o.x = f2_to_bf2(r[0], r[1]); o.y = f2_to_bf2(r[2], r[3]);
        o.z = f2_to_bf2(r[4], r[5]); o.w = f2_to_bf2(r[6], r[7]);
        *(uint4*)(out + (size_t)node * 64 + j * 4) = o;
    }
}

// ---------------- wide aggregation, 64 feats + log_softmax ----------------
// j=lane&7 covers feature octet (16B of the 128B row); g=lane>>3 = 8 edge slots.
__global__ __launch_bounds__(256) void agg_lsm_64_w(
        const unsigned short* __restrict__ T, const int* __restrict__ rowend,
        const int* __restrict__ cnt, const int* __restrict__ col,
        const float* __restrict__ dinv, const float* __restrict__ bias,
        float* __restrict__ out, int n) {
    int node = blockIdx.x * 4 + (threadIdx.x >> 6);
    if (node >= n) return;
    int lane = threadIdx.x & 63;
    int j = lane & 7, g = lane >> 3;
    int end = rowend[node];
    int start = end - cnt[node];
    float di = dinv[node];

    float acc[8];
#pragma unroll
    for (int k = 0; k < 8; ++k) acc[k] = 0.0f;
    if (g == 0) {
        uint4 v = *(const uint4*)(T + (size_t)node * 64 + j * 8);
        acc8_add(acc, v);
    }
    int p = start;
    for (; p + 16 <= end; p += 16) {
        int s0 = col[p + g], s1 = col[p + 8 + g];
        uint4 v0 = *(const uint4*)(T + (size_t)s0 * 64 + j * 8);
        uint4 v1 = *(const uint4*)(T + (size_t)s1 * 64 + j * 8);
        acc8_add(acc, v0); acc8_add(acc, v1);
    }
    for (; p < end; p += 8) {
        int e = p + g;
        if (e < end) {
            int s = col[e];
            uint4 v = *(const uint4*)(T + (size_t)s * 64 + j * 8);
            acc8_add(acc, v);
        }
    }
    // reduce across the 8 edge groups (xor bits 3,4,5 of lane)
#pragma unroll
    for (int k = 0; k < 8; ++k) {
        acc[k] += __shfl_xor(acc[k], 8, 64);
        acc[k] += __shfl_xor(acc[k], 16, 64);
        acc[k] += __shfl_xor(acc[k], 32, 64);
    }
    const float4* b4 = (const float4*)bias;
    float4 ba = b4[j * 2], bb = b4[j * 2 + 1];
    float r[8];
    r[0] = di * acc[0] + ba.x; r[1] = di * acc[1] + ba.y;
    r[2] = di * acc[2] + ba.z; r[3] = di * acc[3] + ba.w;
    r[4] = di * acc[4] + bb.x; r[5] = di * acc[5] + bb.y;
    r[6] = di * acc[6] + bb.z; r[7] = di * acc[7] + bb.w;
    // log_softmax over 64 features: values depend only on j -> reduce over lane bits 0..2
    float m = r[0];
#pragma unroll
    for (int k = 1; k < 8; ++k) m = fmaxf(m, r[k]);
    m = fmaxf(m, __shfl_xor(m, 1, 64));
    m = fmaxf(m, __shfl_xor(m, 2, 64));
    m = fmaxf(m, __shfl_xor(m, 4, 64));
    float ss = 0.0f;
#pragma unroll
    for (int k = 0; k < 8; ++k) ss += expf(r[k] - m);
    ss += __shfl_xor(ss, 1, 64);
    ss += __shfl_xor(ss, 2, 64);
    ss += __shfl_xor(ss, 4, 64);
    float lg = m + logf(ss);
    if (g == 0) {
        float4 o0 = make_float4(r[0] - lg, r[1] - lg, r[2] - lg, r[3] - lg);
        float4 o1 = make_float4(r[4] - lg, r[5] - lg, r[6] - lg, r[7] - lg);
        *(float4*)(out + (size_t)node * 64 + j * 8) = o0;
        *(float4*)(out + (size_t)node * 64 + j * 8 + 4) = o1;
    }
}

// ---------------- launcher ----------------
extern "C" void kernel_launch(void* const* d_in, const int* in_sizes, int n_in,
                              void* d_out, int out_size, void* d_ws, size_t ws_size,
                              hipStream_t stream) {
    const float* x  = (const float*)d_in[0];
    const void*  ei = d_in[1];
    const float* W1 = (const float*)d_in[2];
    const float* b1 = (const float*)d_in[3];
    const float* W2 = (const float*)d_in[4];
    const float* b2 = (const float*)d_in[5];
    const float* W3 = (const float*)d_in[6];
    const float* b3 = (const float*)d_in[7];
    float* out = (float*)d_out;

    const int n = in_sizes[0] / FIN;       // 100000
    const int E = in_sizes[1] / 2;         // 1600000

    char* p = (char*)d_ws;
    auto carve = [&](size_t bytes) {
        char* q = p;
        p += (bytes + 255) & ~(size_t)255;
        return q;
    };
    int*   cnt    = (int*)carve((size_t)n * 4);
    int*   flag   = (int*)carve(256);
    int*   rowend = (int*)carve((size_t)n * 4);
    int*   bsums  = (int*)carve(1024 * 4);
    float* dinv   = (float*)carve((size_t)n * 4);
    int*   colb   = (int*)carve((size_t)E * 4);
    size_t Tbytes = (size_t)n * 128 * 2;   // bf16 n x 128 (also aliased by split bufs)
    void*  T      = (void*)carve(Tbytes);
    unsigned short* Hb = (unsigned short*)carve((size_t)n * 128 * 2);  // bf16
    unsigned short* Wf1 = (unsigned short*)carve(128 * 128 * 2);
    unsigned short* Wf2 = (unsigned short*)carve(128 * 128 * 2);
    unsigned short* Wf3 = (unsigned short*)carve(128 * 64 * 2);

    const int NB = (n + 63) / 64;          // 64-node bins
    const int NS = (n + 8191) / 8192;      // 8192-node super-bins
    int*  gCnt = (int*)carve((size_t)16 * 4);
    int*  cnt2 = (int*)carve((size_t)NB * 4);

    long long meanS = (long long)E * 8192 / n;
    int capS = (int)(meanS + 8 * (long long)sqrt((double)meanS) + 1024);
    capS = (capS + 15) & ~15;
    long long mean2 = (long long)E * 64 / n;
    int cap2 = (int)(mean2 + 8 * (long long)sqrt((double)mean2) + 64);
    cap2 = (cap2 + 15) & ~15;
    size_t buf1B = ((size_t)NS * capS * 8 + 255) & ~(size_t)255;
    uint2*    buf1 = (uint2*)T;
    uint32_t* buf2 = (uint32_t*)((char*)T + buf1B);
    size_t avail2 = (Tbytes > buf1B) ? (Tbytes - buf1B) : 0;
    size_t maxc2 = avail2 / ((size_t)NB * 4);
    if ((size_t)cap2 > maxc2) cap2 = (int)maxc2;

    hipMemsetAsync(flag, 0, 4, stream);
    hipMemsetAsync(gCnt, 0, 16 * 4, stream);
    hipMemsetAsync(cnt2, 0, (size_t)NB * 4, stream);

    const int g256 = (n + 255) / 256;
    const int nbA = (n + SCAN_BS - 1) / SCAN_BS;
    const int gagg = (n + 3) / 4;
    const int ggemm = (n + 63) / 64;
    const int nsamp = E < 65536 ? E : 65536;
    const int gsplitA = (E + SP_CHUNK - 1) / SP_CHUNK;
    const int gsplitBx = (capS + SP_CHUNK - 1) / SP_CHUNK;

    detect_kernel<<<(nsamp + 255) / 256, 256, 0, stream>>>((const int*)ei, flag, nsamp);
    splitA_kernel<<<gsplitA, 256, 0, stream>>>(ei, flag, gCnt, buf1, E, capS);
    splitB_kernel<<<dim3(gsplitBx, NS), 256, 0, stream>>>(gCnt, buf1, cnt2, buf2, capS,
                                                          cap2, NB);
    binB_kernel<<<NB, 256, 0, stream>>>(cnt2, buf2, cnt, n, cap2);
    scan_phaseA<<<nbA, SCAN_BS, 0, stream>>>(cnt, rowend, bsums, n);
    scan_phaseB<<<1, 128, 0, stream>>>(bsums, nbA);
    scan_phaseC<<<g256, 256, 0, stream>>>(rowend, bsums, n);
    dinv_kernel<<<g256, 256, 0, stream>>>(cnt, dinv, n);
    binC_kernel<<<NB, 256, 0, stream>>>(cnt2, buf2, rowend, cnt, colb, n, cap2);
    wconv_all<<<20, 256, 0, stream>>>(W1, W2, W3, Wf1, Wf2, Wf3);

    // layer 1: T'(bf16) = dinv * (x @ W1) ; Hb(bf16) = relu(di*(sum T') + b1)
    gemm_mfma<128, 1><<<ggemm, 256, 0, stream>>>(x, Wf1, dinv, (unsigned short*)T, n);
    agg_relu_128_w<<<gagg, 256, 0, stream>>>((const unsigned short*)T, rowend, cnt,
                                             colb, dinv, b1, (uint32_t*)Hb, n, 1);
    // layer 2
    gemm_mfma<128, 0><<<ggemm, 256, 0, stream>>>(Hb, Wf2, dinv, (unsigned short*)T, n);
    agg_relu_128_w<<<gagg, 256, 0, stream>>>((const unsigned short*)T, rowend, cnt,
                                             colb, dinv, b2, (uint32_t*)Hb, n, 1);
    // layer 3
    gemm_mfma<64, 0><<<ggemm, 256, 0, stream>>>(Hb, Wf3, dinv, (unsigned short*)T, n);
    agg_lsm_64_w<<<gagg, 256, 0, stream>>>((const unsigned short*)T, rowend, cnt,
                                           colb, dinv, b3, out, n);
}

// Round 8
// 371.681 us; speedup vs baseline: 1.9864x; 1.0536x over previous
//
#include <hip/hip_runtime.h>
#include <stdint.h>
#include <math.h>

#define FIN 128

typedef __attribute__((ext_vector_type(8))) short short8v;
typedef __attribute__((ext_vector_type(4))) float float4v;

// ---------------- bf16 helpers (manual, RNE) ----------------
__device__ __forceinline__ float2 bf2_to_f2(uint32_t u) {
    union { uint32_t i; float f; } a, b;
    a.i = (u & 0xFFFFu) << 16;
    b.i = u & 0xFFFF0000u;
    return make_float2(a.f, b.f);
}
__device__ __forceinline__ uint32_t f2_to_bf2(float x, float y) {
    union { float f; uint32_t i; } a, b;
    a.f = x; b.f = y;
    uint32_t ax = a.i + 0x7FFF + ((a.i >> 16) & 1);
    uint32_t by = b.i + 0x7FFF + ((b.i >> 16) & 1);
    return (ax >> 16) | (by & 0xFFFF0000u);
}
__device__ __forceinline__ unsigned short f_to_bf(float x) {
    union { float f; uint32_t i; } a;
    a.f = x;
    uint32_t u = a.i + 0x7FFF + ((a.i >> 16) & 1);
    return (unsigned short)(u >> 16);
}
// acc[k] += w * bf16[k] for 8 bf16 in uint4 (w=0 masks out-of-range edges)
__device__ __forceinline__ void acc8_fma(float* acc, uint4 v, float w) {
    float2 f;
    f = bf2_to_f2(v.x); acc[0] = fmaf(w, f.x, acc[0]); acc[1] = fmaf(w, f.y, acc[1]);
    f = bf2_to_f2(v.y); acc[2] = fmaf(w, f.x, acc[2]); acc[3] = fmaf(w, f.y, acc[3]);
    f = bf2_to_f2(v.z); acc[4] = fmaf(w, f.x, acc[4]); acc[5] = fmaf(w, f.y, acc[5]);
    f = bf2_to_f2(v.w); acc[6] = fmaf(w, f.x, acc[6]); acc[7] = fmaf(w, f.y, acc[7]);
}

// ---------------- edge dtype detection ----------------
__global__ __launch_bounds__(256) void detect_kernel(const int* __restrict__ ei32,
                                                     int* __restrict__ flag, int nsamp) {
    int i = blockIdx.x * 256 + threadIdx.x;
    if (i < nsamp) {
        if (ei32[2 * i + 1] != 0) atomicOr(flag, 1);
    }
}

__device__ __forceinline__ int edge_at(const void* ei, long long idx, int is32) {
    return is32 ? ((const int*)ei)[idx] : (int)((const long long*)ei)[idx];
}

// ---------------- Level-1 split: 16 super-bins (dst>>13) ----------------
#define SP_CHUNK 4096
__global__ __launch_bounds__(256) void splitA_kernel(const void* __restrict__ ei,
                                                     const int* __restrict__ flag,
                                                     int* __restrict__ gCnt,
                                                     uint2* __restrict__ buf1,
                                                     int E, int capS) {
    __shared__ int hist[16];
    __shared__ int gbase[16];
    int t = threadIdx.x;
    if (t < 16) hist[t] = 0;
    __syncthreads();
    int is32 = *flag;
    long long base = (long long)blockIdx.x * SP_CHUNK;
    uint32_t lrec[16], rs[16], rd[16];
#pragma unroll
    for (int j = 0; j < 16; ++j) {
        long long e = base + t + j * 256;
        if (e < E) {
            int s = edge_at(ei, e, is32);
            int d = edge_at(ei, (long long)E + e, is32);
            int b = d >> 13;
            int lofs = atomicAdd(&hist[b], 1);
            lrec[j] = ((uint32_t)lofs << 4) | (uint32_t)b;
            rs[j] = (uint32_t)s;
            rd[j] = (uint32_t)d;
        } else
            lrec[j] = 0xFFFFFFFFu;
    }
    __syncthreads();
    if (t < 16) gbase[t] = atomicAdd(&gCnt[t], hist[t]);
    __syncthreads();
#pragma unroll
    for (int j = 0; j < 16; ++j) {
        if (lrec[j] != 0xFFFFFFFFu) {
            int b = lrec[j] & 15;
            int pos = gbase[b] + (int)(lrec[j] >> 4);
            if (pos < capS) buf1[(size_t)b * capS + pos] = make_uint2(rs[j], rd[j]);
        }
    }
}

// ---------------- Level-2 split: 128 sub-bins of 64 nodes ----------------
__global__ __launch_bounds__(256) void splitB_kernel(const int* __restrict__ gCnt,
                                                     const uint2* __restrict__ buf1,
                                                     int* __restrict__ cnt2,
                                                     uint32_t* __restrict__ buf2,
                                                     int capS, int cap2, int NB) {
    __shared__ int hist[128];
    __shared__ int gbase[128];
    int t = threadIdx.x;
    int s = blockIdx.y;
    if (t < 128) hist[t] = 0;
    __syncthreads();
    int m = gCnt[s];
    if (m > capS) m = capS;
    long long base = (long long)blockIdx.x * SP_CHUNK;
    uint32_t lrec[16], r32[16];
#pragma unroll
    for (int j = 0; j < 16; ++j) {
        long long i = base + t + j * 256;
        if (i < m) {
            uint2 r = buf1[(size_t)s * capS + i];
            int d = (int)r.y;
            int sub = (d >> 6) & 127;
            int lofs = atomicAdd(&hist[sub], 1);
            lrec[j] = ((uint32_t)lofs << 7) | (uint32_t)sub;
            r32[j] = (r.x << 6) | (uint32_t)(d & 63);
        } else
            lrec[j] = 0xFFFFFFFFu;
    }
    __syncthreads();
    if (t < 128) {
        int g = s * 128 + t;
        gbase[t] = (g < NB) ? atomicAdd(&cnt2[g], hist[t]) : 0;
    }
    __syncthreads();
#pragma unroll
    for (int j = 0; j < 16; ++j) {
        if (lrec[j] != 0xFFFFFFFFu) {
            int sub = lrec[j] & 127;
            int pos = gbase[sub] + (int)(lrec[j] >> 7);
            if (pos < cap2) buf2[(size_t)(s * 128 + sub) * cap2 + pos] = r32[j];
        }
    }
}

// ---------------- per-node degree + dinv via LDS histogram ----------------
__global__ __launch_bounds__(256) void binB_kernel(const int* __restrict__ cnt2,
                                                   const uint32_t* __restrict__ buf2,
                                                   int* __restrict__ cnt,
                                                   float* __restrict__ dinv,
                                                   int n, int cap2) {
    __shared__ int h[64];
    int bin = blockIdx.x;
    int t = threadIdx.x;
    if (t < 64) h[t] = 0;
    __syncthreads();
    int m = cnt2[bin];
    if (m > cap2) m = cap2;
    const uint32_t* buf = buf2 + (size_t)bin * cap2;
    for (int i = t; i < m; i += 256) atomicAdd(&h[buf[i] & 63], 1);
    __syncthreads();
    if (t < 64) {
        int node = bin * 64 + t;
        if (node < n) {
            cnt[node] = h[t];
            dinv[node] = rsqrtf((float)h[t] + 1.0f);
        }
    }
}

// ---------------- 3-phase scan (inclusive) ----------------
#define SCAN_BS 1024
__global__ __launch_bounds__(SCAN_BS) void scan_phaseA(const int* __restrict__ cnt,
                                                       int* __restrict__ incl,
                                                       int* __restrict__ bsums, int n) {
    __shared__ int sm[SCAN_BS];
    int gid = blockIdx.x * SCAN_BS + threadIdx.x;
    int v = (gid < n) ? cnt[gid] : 0;
    sm[threadIdx.x] = v;
    __syncthreads();
    for (int off = 1; off < SCAN_BS; off <<= 1) {
        int t = 0;
        if ((int)threadIdx.x >= off) t = sm[threadIdx.x - off];
        __syncthreads();
        sm[threadIdx.x] += t;
        __syncthreads();
    }
    if (gid < n) incl[gid] = sm[threadIdx.x];
    if (threadIdx.x == SCAN_BS - 1) bsums[blockIdx.x] = sm[threadIdx.x];
}

__global__ __launch_bounds__(128) void scan_phaseB(int* __restrict__ bsums, int nb) {
    __shared__ int sm[128];
    int v = ((int)threadIdx.x < nb) ? bsums[threadIdx.x] : 0;
    sm[threadIdx.x] = v;
    __syncthreads();
    for (int off = 1; off < 128; off <<= 1) {
        int t = 0;
        if ((int)threadIdx.x >= off) t = sm[threadIdx.x - off];
        __syncthreads();
        sm[threadIdx.x] += t;
        __syncthreads();
    }
    if ((int)threadIdx.x < nb)
        bsums[threadIdx.x] = (threadIdx.x == 0) ? 0 : sm[threadIdx.x - 1];
}

__global__ __launch_bounds__(256) void scan_phaseC(int* __restrict__ incl,
                                                   const int* __restrict__ bsums, int n) {
    int gid = blockIdx.x * 256 + threadIdx.x;
    if (gid < n) incl[gid] += bsums[gid >> 10];
}

// ---------------- scatter bin records into CSR ----------------
__global__ __launch_bounds__(256) void binC_kernel(const int* __restrict__ cnt2,
                                                   const uint32_t* __restrict__ buf2,
                                                   const int* __restrict__ rowend,
                                                   const int* __restrict__ cnt,
                                                   int* __restrict__ col, int n, int cap2) {
    __shared__ int rowst[64];
    __shared__ int cur[64];
    int bin = blockIdx.x;
    int t = threadIdx.x;
    if (t < 64) {
        cur[t] = 0;
        int node = bin * 64 + t;
        rowst[t] = (node < n) ? rowend[node] - cnt[node] : 0;
    }
    __syncthreads();
    int m = cnt2[bin];
    if (m > cap2) m = cap2;
    const uint32_t* buf = buf2 + (size_t)bin * cap2;
    for (int i = t; i < m; i += 256) {
        uint32_t rec = buf[i];
        int d6 = rec & 63;
        int off = atomicAdd(&cur[d6], 1);
        col[rowst[d6] + off] = (int)(rec >> 6);
    }
}

// ---------------- W -> fragment-ordered bf16 ----------------
__global__ __launch_bounds__(256) void wconv_all(const float* __restrict__ W1,
                                                 const float* __restrict__ W2,
                                                 const float* __restrict__ W3,
                                                 unsigned short* __restrict__ Wf1,
                                                 unsigned short* __restrict__ Wf2,
                                                 unsigned short* __restrict__ Wf3) {
    int idx = blockIdx.x * 256 + threadIdx.x;
    const float* W;
    unsigned short* Wf;
    int NCOL, base;
    if (idx < 2048)      { W = W1; Wf = Wf1; NCOL = 128; base = idx; }
    else if (idx < 4096) { W = W2; Wf = Wf2; NCOL = 128; base = idx - 2048; }
    else if (idx < 5120) { W = W3; Wf = Wf3; NCOL = 64;  base = idx - 4096; }
    else return;
    int f = base >> 6, l = base & 63;
    int ct = f >> 2, ks = f & 3;
    int nn = ct * 16 + (l & 15);
    int k0 = ks * 32 + (l >> 4) * 8;
    uint32_t pk[4];
#pragma unroll
    for (int j = 0; j < 4; ++j) {
        float a = W[(size_t)(k0 + 2 * j) * NCOL + nn];
        float b = W[(size_t)(k0 + 2 * j + 1) * NCOL + nn];
        pk[j] = f2_to_bf2(a, b);
    }
    uint4 v = make_uint4(pk[0], pk[1], pk[2], pk[3]);
    ((uint4*)Wf)[base] = v;
}

// ---------------- MFMA GEMM + dinv row-scale epilogue ----------------
template <int NCOL, int A_FP32>
__global__ __launch_bounds__(256) void gemm_mfma(const void* __restrict__ Av,
                                                 const unsigned short* __restrict__ Wf,
                                                 const float* __restrict__ dinv,
                                                 unsigned short* __restrict__ C, int n) {
    __shared__ unsigned short lds[NCOL * 128];
    const int t = threadIdx.x;
    for (int i = t; i < NCOL * 16; i += 256)
        ((uint4*)lds)[i] = ((const uint4*)Wf)[i];
    __syncthreads();

    const int wave = t >> 6, lane = t & 63;
    const int row0 = blockIdx.x * 64 + wave * 16;
    const int m = lane & 15, quad = lane >> 4;
    int arow = row0 + m;
    if (arow >= n) arow = n - 1;

    short8v a[4];
    if (A_FP32) {
        const float* A = (const float*)Av;
#pragma unroll
        for (int ks = 0; ks < 4; ++ks) {
            float4 lo = *(const float4*)(A + (size_t)arow * 128 + ks * 32 + quad * 8);
            float4 hi = *(const float4*)(A + (size_t)arow * 128 + ks * 32 + quad * 8 + 4);
            union { short8v v; uint32_t u[4]; } pk;
            pk.u[0] = f2_to_bf2(lo.x, lo.y);
            pk.u[1] = f2_to_bf2(lo.z, lo.w);
            pk.u[2] = f2_to_bf2(hi.x, hi.y);
            pk.u[3] = f2_to_bf2(hi.z, hi.w);
            a[ks] = pk.v;
        }
    } else {
        const unsigned short* A = (const unsigned short*)Av;
#pragma unroll
        for (int ks = 0; ks < 4; ++ks)
            a[ks] = *(const short8v*)(A + (size_t)arow * 128 + ks * 32 + quad * 8);
    }

    const int cr0 = row0 + quad * 4;
    float ds[4];
#pragma unroll
    for (int r = 0; r < 4; ++r) {
        int gr = cr0 + r;
        ds[r] = (gr < n) ? dinv[gr] : 0.0f;
    }
#pragma unroll
    for (int ct = 0; ct < NCOL / 16; ++ct) {
        float4v acc = {0.0f, 0.0f, 0.0f, 0.0f};
#pragma unroll
        for (int ks = 0; ks < 4; ++ks) {
            int f = ct * 4 + ks;
            short8v b = *(const short8v*)(lds + ((size_t)(f * 64 + lane)) * 8);
            acc = __builtin_amdgcn_mfma_f32_16x16x32_bf16(a[ks], b, acc, 0, 0, 0);
        }
#pragma unroll
        for (int r = 0; r < 4; ++r) {
            int gr = cr0 + r;
            if (gr < n) C[(size_t)gr * NCOL + ct * 16 + m] = f_to_bf(acc[r] * ds[r]);
        }
    }
}

// ---------------- 2-node wide aggregation, 128 feats (T' pre-scaled by dinv) --------
// wave = 2 nodes. j=lane&15 = feature octet, g=lane>>4 = edge slot (4 per node).
// All gathers use clamped indices + mask-weight fma -> 4 loads in flight always.
__global__ __launch_bounds__(256) void agg_relu_128_w2(
        const unsigned short* __restrict__ T, const int* __restrict__ rowend,
        const int* __restrict__ cnt, const int* __restrict__ col,
        const float* __restrict__ dinv, const float* __restrict__ bias,
        uint32_t* __restrict__ out, int n, int do_relu) {
    int wid = blockIdx.x * 4 + (threadIdx.x >> 6);
    int nodeA = wid * 2, nodeB = wid * 2 + 1;
    if (nodeA >= n) return;
    int lane = threadIdx.x & 63;
    int j = lane & 15, g = lane >> 4;
    int endA = rowend[nodeA];
    int startA = endA - cnt[nodeA];
    int endB = endA, startB = endA;
    if (nodeB < n) { endB = rowend[nodeB]; startB = endB - cnt[nodeB]; }

    float accA[8], accB[8];
#pragma unroll
    for (int k = 0; k < 8; ++k) { accA[k] = 0.0f; accB[k] = 0.0f; }
    // self loops (g==0 -> A, g==1 -> B); cross-g reduce sums them in
    if (g == 0) {
        uint4 v = *(const uint4*)(T + (size_t)nodeA * 128 + j * 8);
        acc8_fma(accA, v, 1.0f);
    } else if (g == 1 && nodeB < n) {
        uint4 v = *(const uint4*)(T + (size_t)nodeB * 128 + j * 8);
        acc8_fma(accB, v, 1.0f);
    }

    int degA = endA - startA, degB = endB - startB;
    int degM = degA > degB ? degA : degB;
    int pA = startA + g, pB = startB + g;
    for (int it = 0; it < degM; it += 8) {
        int eA0 = pA, eA1 = pA + 4, eB0 = pB, eB1 = pB + 4;
        float wA0 = eA0 < endA ? 1.0f : 0.0f;
        float wA1 = eA1 < endA ? 1.0f : 0.0f;
        float wB0 = eB0 < endB ? 1.0f : 0.0f;
        float wB1 = eB1 < endB ? 1.0f : 0.0f;
        int cA0 = min(eA0, endA - 1); cA0 = max(cA0, 0);
        int cA1 = min(eA1, endA - 1); cA1 = max(cA1, 0);
        int cB0 = min(eB0, endB - 1); cB0 = max(cB0, 0);
        int cB1 = min(eB1, endB - 1); cB1 = max(cB1, 0);
        int sA0 = col[cA0], sA1 = col[cA1], sB0 = col[cB0], sB1 = col[cB1];
        uint4 vA0 = *(const uint4*)(T + (size_t)sA0 * 128 + j * 8);
        uint4 vA1 = *(const uint4*)(T + (size_t)sA1 * 128 + j * 8);
        uint4 vB0 = *(const uint4*)(T + (size_t)sB0 * 128 + j * 8);
        uint4 vB1 = *(const uint4*)(T + (size_t)sB1 * 128 + j * 8);
        acc8_fma(accA, vA0, wA0);
        acc8_fma(accA, vA1, wA1);
        acc8_fma(accB, vB0, wB0);
        acc8_fma(accB, vB1, wB1);
        pA += 8; pB += 8;
    }
    // reduce across the 4 edge slots
#pragma unroll
    for (int k = 0; k < 8; ++k) {
        accA[k] += __shfl_xor(accA[k], 16, 64);
        accA[k] += __shfl_xor(accA[k], 32, 64);
        accB[k] += __shfl_xor(accB[k], 16, 64);
        accB[k] += __shfl_xor(accB[k], 32, 64);
    }
    if (g < 2) {
        int node = (g == 0) ? nodeA : nodeB;
        if (node < n) {
            float di = dinv[node];
            const float* acc = (g == 0) ? accA : accB;
            const float4* b4 = (const float4*)bias;
            float4 ba = b4[j * 2], bb = b4[j * 2 + 1];
            float r[8];
            r[0] = di * acc[0] + ba.x; r[1] = di * acc[1] + ba.y;
            r[2] = di * acc[2] + ba.z; r[3] = di * acc[3] + ba.w;
            r[4] = di * acc[4] + bb.x; r[5] = di * acc[5] + bb.y;
            r[6] = di * acc[6] + bb.z; r[7] = di * acc[7] + bb.w;
            if (do_relu)
#pragma unroll
                for (int k = 0; k < 8; ++k) r[k] = fmaxf(r[k], 0.0f);
            uint4 o;
            o.x = f2_to_bf2(r[0], r[1]); o.y = f2_to_bf2(r[2], r[3]);
            o.z = f2_to_bf2(r[4], r[5]); o.w = f2_to_bf2(r[6], r[7]);
            *(uint4*)(out + (size_t)node * 64 + j * 4) = o;
        }
    }
}

// ---------------- 2-node wide aggregation, 64 feats + log_softmax ----------------
// half-wave per node: sel=lane>>5, slot=(lane>>3)&3, j=lane&7 (feature octet).
__global__ __launch_bounds__(256) void agg_lsm_64_w2(
        const unsigned short* __restrict__ T, const int* __restrict__ rowend,
        const int* __restrict__ cnt, const int* __restrict__ col,
        const float* __restrict__ dinv, const float* __restrict__ bias,
        float* __restrict__ out, int n) {
    int wid = blockIdx.x * 4 + (threadIdx.x >> 6);
    int lane = threadIdx.x & 63;
    int sel = lane >> 5, slot = (lane >> 3) & 3, j = lane & 7;
    int node = wid * 2 + sel;
    int nodeA = wid * 2;
    if (nodeA >= n) return;
    bool valid = node < n;
    int nd = valid ? node : nodeA;
    int end = rowend[nd];
    int start = end - cnt[nd];
    if (!valid) start = end;   // empty row for the padded node

    float acc[8];
#pragma unroll
    for (int k = 0; k < 8; ++k) acc[k] = 0.0f;
    if (slot == 0 && valid) {
        uint4 v = *(const uint4*)(T + (size_t)node * 64 + j * 8);
        acc8_fma(acc, v, 1.0f);
    }
    int deg = end - start;
    int degM = max(deg, __shfl_xor(deg, 32, 64));
    int p = start + slot;
    for (int it = 0; it < degM; it += 8) {
        int e0 = p, e1 = p + 4;
        float w0 = e0 < end ? 1.0f : 0.0f;
        float w1 = e1 < end ? 1.0f : 0.0f;
        int c0 = min(e0, end - 1); c0 = max(c0, 0);
        int c1 = min(e1, end - 1); c1 = max(c1, 0);
        int s0 = col[c0], s1 = col[c1];
        uint4 v0 = *(const uint4*)(T + (size_t)s0 * 64 + j * 8);
        uint4 v1 = *(const uint4*)(T + (size_t)s1 * 64 + j * 8);
        acc8_fma(acc, v0, w0);
        acc8_fma(acc, v1, w1);
        p += 8;
    }
    // reduce across the 4 slots (lane bits 3,4) within each half
#pragma unroll
    for (int k = 0; k < 8; ++k) {
        acc[k] += __shfl_xor(acc[k], 8, 64);
        acc[k] += __shfl_xor(acc[k], 16, 64);
    }
    float di = dinv[nd];
    const float4* b4 = (const float4*)bias;
    float4 ba = b4[j * 2], bb = b4[j * 2 + 1];
    float r[8];
    r[0] = di * acc[0] + ba.x; r[1] = di * acc[1] + ba.y;
    r[2] = di * acc[2] + ba.z; r[3] = di * acc[3] + ba.w;
    r[4] = di * acc[4] + bb.x; r[5] = di * acc[5] + bb.y;
    r[6] = di * acc[6] + bb.z; r[7] = di * acc[7] + bb.w;
    // log_softmax over 64 features (reduce over j = lane bits 0..2, within half)
    float m = r[0];
#pragma unroll
    for (int k = 1; k < 8; ++k) m = fmaxf(m, r[k]);
    m = fmaxf(m, __shfl_xor(m, 1, 64));
    m = fmaxf(m, __shfl_xor(m, 2, 64));
    m = fmaxf(m, __shfl_xor(m, 4, 64));
    float ss = 0.0f;
#pragma unroll
    for (int k = 0; k < 8; ++k) ss += expf(r[k] - m);
    ss += __shfl_xor(ss, 1, 64);
    ss += __shfl_xor(ss, 2, 64);
    ss += __shfl_xor(ss, 4, 64);
    float lg = m + logf(ss);
    if (slot == 0 && valid) {
        float4 o0 = make_float4(r[0] - lg, r[1] - lg, r[2] - lg, r[3] - lg);
        float4 o1 = make_float4(r[4] - lg, r[5] - lg, r[6] - lg, r[7] - lg);
        *(float4*)(out + (size_t)node * 64 + j * 8) = o0;
        *(float4*)(out + (size_t)node * 64 + j * 8 + 4) = o1;
    }
}

// ---------------- launcher ----------------
extern "C" void kernel_launch(void* const* d_in, const int* in_sizes, int n_in,
                              void* d_out, int out_size, void* d_ws, size_t ws_size,
                              hipStream_t stream) {
    const float* x  = (const float*)d_in[0];
    const void*  ei = d_in[1];
    const float* W1 = (const float*)d_in[2];
    const float* b1 = (const float*)d_in[3];
    const float* W2 = (const float*)d_in[4];
    const float* b2 = (const float*)d_in[5];
    const float* W3 = (const float*)d_in[6];
    const float* b3 = (const float*)d_in[7];
    float* out = (float*)d_out;

    const int n = in_sizes[0] / FIN;       // 100000
    const int E = in_sizes[1] / 2;         // 1600000

    char* p = (char*)d_ws;
    auto carve = [&](size_t bytes) {
        char* q = p;
        p += (bytes + 255) & ~(size_t)255;
        return q;
    };
    int*   cnt    = (int*)carve((size_t)n * 4);
    int*   flag   = (int*)carve(256);
    int*   rowend = (int*)carve((size_t)n * 4);
    int*   bsums  = (int*)carve(1024 * 4);
    float* dinv   = (float*)carve((size_t)n * 4);
    int*   colb   = (int*)carve((size_t)E * 4);
    size_t Tbytes = (size_t)n * 128 * 2;   // bf16 n x 128 (also aliased by split bufs)
    void*  T      = (void*)carve(Tbytes);
    unsigned short* Hb = (unsigned short*)carve((size_t)n * 128 * 2);  // bf16
    unsigned short* Wf1 = (unsigned short*)carve(128 * 128 * 2);
    unsigned short* Wf2 = (unsigned short*)carve(128 * 128 * 2);
    unsigned short* Wf3 = (unsigned short*)carve(128 * 64 * 2);

    const int NB = (n + 63) / 64;          // 64-node bins
    const int NS = (n + 8191) / 8192;      // 8192-node super-bins
    int*  gCnt = (int*)carve((size_t)16 * 4);
    int*  cnt2 = (int*)carve((size_t)NB * 4);

    long long meanS = (long long)E * 8192 / n;
    int capS = (int)(meanS + 8 * (long long)sqrt((double)meanS) + 1024);
    capS = (capS + 15) & ~15;
    long long mean2 = (long long)E * 64 / n;
    int cap2 = (int)(mean2 + 8 * (long long)sqrt((double)mean2) + 64);
    cap2 = (cap2 + 15) & ~15;
    size_t buf1B = ((size_t)NS * capS * 8 + 255) & ~(size_t)255;
    uint2*    buf1 = (uint2*)T;
    uint32_t* buf2 = (uint32_t*)((char*)T + buf1B);
    size_t avail2 = (Tbytes > buf1B) ? (Tbytes - buf1B) : 0;
    size_t maxc2 = avail2 / ((size_t)NB * 4);
    if ((size_t)cap2 > maxc2) cap2 = (int)maxc2;

    hipMemsetAsync(flag, 0, 4, stream);
    hipMemsetAsync(gCnt, 0, 16 * 4, stream);
    hipMemsetAsync(cnt2, 0, (size_t)NB * 4, stream);

    const int g256 = (n + 255) / 256;
    const int nbA = (n + SCAN_BS - 1) / SCAN_BS;
    const int gagg2 = ((n + 1) / 2 + 3) / 4;     // 2 nodes per wave
    const int ggemm = (n + 63) / 64;
    const int nsamp = E < 65536 ? E : 65536;
    const int gsplitA = (E + SP_CHUNK - 1) / SP_CHUNK;
    const int gsplitBx = (capS + SP_CHUNK - 1) / SP_CHUNK;

    detect_kernel<<<(nsamp + 255) / 256, 256, 0, stream>>>((const int*)ei, flag, nsamp);
    splitA_kernel<<<gsplitA, 256, 0, stream>>>(ei, flag, gCnt, buf1, E, capS);
    splitB_kernel<<<dim3(gsplitBx, NS), 256, 0, stream>>>(gCnt, buf1, cnt2, buf2, capS,
                                                          cap2, NB);
    binB_kernel<<<NB, 256, 0, stream>>>(cnt2, buf2, cnt, dinv, n, cap2);
    scan_phaseA<<<nbA, SCAN_BS, 0, stream>>>(cnt, rowend, bsums, n);
    scan_phaseB<<<1, 128, 0, stream>>>(bsums, nbA);
    scan_phaseC<<<g256, 256, 0, stream>>>(rowend, bsums, n);
    binC_kernel<<<NB, 256, 0, stream>>>(cnt2, buf2, rowend, cnt, colb, n, cap2);
    wconv_all<<<20, 256, 0, stream>>>(W1, W2, W3, Wf1, Wf2, Wf3);

    // layer 1: T'(bf16) = dinv * (x @ W1) ; Hb(bf16) = relu(di*(sum T') + b1)
    gemm_mfma<128, 1><<<ggemm, 256, 0, stream>>>(x, Wf1, dinv, (unsigned short*)T, n);
    agg_relu_128_w2<<<gagg2, 256, 0, stream>>>((const unsigned short*)T, rowend, cnt,
                                               colb, dinv, b1, (uint32_t*)Hb, n, 1);
    // layer 2
    gemm_mfma<128, 0><<<ggemm, 256, 0, stream>>>(Hb, Wf2, dinv, (unsigned short*)T, n);
    agg_relu_128_w2<<<gagg2, 256, 0, stream>>>((const unsigned short*)T, rowend, cnt,
                                               colb, dinv, b2, (uint32_t*)Hb, n, 1);
    // layer 3
    gemm_mfma<64, 0><<<ggemm, 256, 0, stream>>>(Hb, Wf3, dinv, (unsigned short*)T, n);
    agg_lsm_64_w2<<<gagg2, 256, 0, stream>>>((const unsigned short*)T, rowend, cnt,
                                             colb, dinv, b3, out, n);
}

// Round 9
// 305.478 us; speedup vs baseline: 2.4169x; 1.2167x over previous
//
#include <hip/hip_runtime.h>
#include <stdint.h>
#include <math.h>

#define FIN 128

typedef __attribute__((ext_vector_type(8))) short short8v;
typedef __attribute__((ext_vector_type(4))) float float4v;
typedef __attribute__((ext_vector_type(2))) float float2v;

// ---------------- bf16 helpers (manual, RNE) ----------------
__device__ __forceinline__ float2 bf2_to_f2(uint32_t u) {
    union { uint32_t i; float f; } a, b;
    a.i = (u & 0xFFFFu) << 16;
    b.i = u & 0xFFFF0000u;
    return make_float2(a.f, b.f);
}
__device__ __forceinline__ uint32_t f2_to_bf2(float x, float y) {
    union { float f; uint32_t i; } a, b;
    a.f = x; b.f = y;
    uint32_t ax = a.i + 0x7FFF + ((a.i >> 16) & 1);
    uint32_t by = b.i + 0x7FFF + ((b.i >> 16) & 1);
    return (ax >> 16) | (by & 0xFFFF0000u);
}
__device__ __forceinline__ unsigned short f_to_bf(float x) {
    union { float f; uint32_t i; } a;
    a.f = x;
    uint32_t u = a.i + 0x7FFF + ((a.i >> 16) & 1);
    return (unsigned short)(u >> 16);
}
// acc[k] += w * bf16[k] for 8 bf16 in uint4
__device__ __forceinline__ void acc8_fma(float* acc, uint4 v, float w) {
    float2 f;
    f = bf2_to_f2(v.x); acc[0] = fmaf(w, f.x, acc[0]); acc[1] = fmaf(w, f.y, acc[1]);
    f = bf2_to_f2(v.y); acc[2] = fmaf(w, f.x, acc[2]); acc[3] = fmaf(w, f.y, acc[3]);
    f = bf2_to_f2(v.z); acc[4] = fmaf(w, f.x, acc[4]); acc[5] = fmaf(w, f.y, acc[5]);
    f = bf2_to_f2(v.w); acc[6] = fmaf(w, f.x, acc[6]); acc[7] = fmaf(w, f.y, acc[7]);
}
// acc[k] += w * fp8[k] for 16 fp8-e4m3 in uint4 (HW cvt)
__device__ __forceinline__ void acc16_fp8_fma(float* acc, uint4 v, float w) {
    uint32_t us[4] = {v.x, v.y, v.z, v.w};
#pragma unroll
    for (int q = 0; q < 4; ++q) {
        float2v f0 = __builtin_amdgcn_cvt_pk_f32_fp8(us[q], false);
        float2v f1 = __builtin_amdgcn_cvt_pk_f32_fp8(us[q], true);
        acc[q * 4 + 0] = fmaf(w, f0.x, acc[q * 4 + 0]);
        acc[q * 4 + 1] = fmaf(w, f0.y, acc[q * 4 + 1]);
        acc[q * 4 + 2] = fmaf(w, f1.x, acc[q * 4 + 2]);
        acc[q * 4 + 3] = fmaf(w, f1.y, acc[q * 4 + 3]);
    }
}

__device__ __forceinline__ int edge_at(const void* ei, long long idx, int is32) {
    return is32 ? ((const int*)ei)[idx] : (int)((const long long*)ei)[idx];
}

// ---------------- Level-1 split (16 super-bins, dst>>13) + inline dtype detect ------
#define SP_CHUNK 4096
__global__ __launch_bounds__(256) void splitA_kernel(const void* __restrict__ ei,
                                                     int* __restrict__ gCnt,
                                                     uint2* __restrict__ buf1,
                                                     int E, int capS) {
    __shared__ int hist[16];
    __shared__ int gbase[16];
    __shared__ int lflag;
    int t = threadIdx.x;
    if (t < 16) hist[t] = 0;
    if (t == 0) lflag = 0;
    long long base = (long long)blockIdx.x * SP_CHUNK;
    __syncthreads();
    // detect: int64 layout has all odd dwords == 0 (ids < 2^31). Sample 256 edges.
    {
        long long e = base + t;
        if (e < E && ((const int*)ei)[2 * e + 1] != 0) atomicOr(&lflag, 1);
    }
    __syncthreads();
    int is32 = lflag;
    uint32_t lrec[16], rs[16], rd[16];
#pragma unroll
    for (int j = 0; j < 16; ++j) {
        long long e = base + t + j * 256;
        if (e < E) {
            int s = edge_at(ei, e, is32);
            int d = edge_at(ei, (long long)E + e, is32);
            int b = d >> 13;
            int lofs = atomicAdd(&hist[b], 1);
            lrec[j] = ((uint32_t)lofs << 4) | (uint32_t)b;
            rs[j] = (uint32_t)s;
            rd[j] = (uint32_t)d;
        } else
            lrec[j] = 0xFFFFFFFFu;
    }
    __syncthreads();
    if (t < 16) gbase[t] = atomicAdd(&gCnt[t], hist[t]);
    __syncthreads();
#pragma unroll
    for (int j = 0; j < 16; ++j) {
        if (lrec[j] != 0xFFFFFFFFu) {
            int b = lrec[j] & 15;
            int pos = gbase[b] + (int)(lrec[j] >> 4);
            if (pos < capS) buf1[(size_t)b * capS + pos] = make_uint2(rs[j], rd[j]);
        }
    }
}

// ---------------- Level-2 split: 128 sub-bins of 64 nodes ----------------
__global__ __launch_bounds__(256) void splitB_kernel(const int* __restrict__ gCnt,
                                                     const uint2* __restrict__ buf1,
                                                     int* __restrict__ cnt2,
                                                     uint32_t* __restrict__ buf2,
                                                     int capS, int cap2, int NB) {
    __shared__ int hist[128];
    __shared__ int gbase[128];
    int t = threadIdx.x;
    int s = blockIdx.y;
    if (t < 128) hist[t] = 0;
    __syncthreads();
    int m = gCnt[s];
    if (m > capS) m = capS;
    long long base = (long long)blockIdx.x * SP_CHUNK;
    uint32_t lrec[16], r32[16];
#pragma unroll
    for (int j = 0; j < 16; ++j) {
        long long i = base + t + j * 256;
        if (i < m) {
            uint2 r = buf1[(size_t)s * capS + i];
            int d = (int)r.y;
            int sub = (d >> 6) & 127;
            int lofs = atomicAdd(&hist[sub], 1);
            lrec[j] = ((uint32_t)lofs << 7) | (uint32_t)sub;
            r32[j] = (r.x << 6) | (uint32_t)(d & 63);
        } else
            lrec[j] = 0xFFFFFFFFu;
    }
    __syncthreads();
    if (t < 128) {
        int g = s * 128 + t;
        gbase[t] = (g < NB) ? atomicAdd(&cnt2[g], hist[t]) : 0;
    }
    __syncthreads();
#pragma unroll
    for (int j = 0; j < 16; ++j) {
        if (lrec[j] != 0xFFFFFFFFu) {
            int sub = lrec[j] & 127;
            int pos = gbase[sub] + (int)(lrec[j] >> 7);
            if (pos < cap2) buf2[(size_t)(s * 128 + sub) * cap2 + pos] = r32[j];
        }
    }
}

// ---------------- per-node degree + dinv via LDS histogram ----------------
__global__ __launch_bounds__(256) void binB_kernel(const int* __restrict__ cnt2,
                                                   const uint32_t* __restrict__ buf2,
                                                   int* __restrict__ cnt,
                                                   float* __restrict__ dinv,
                                                   int n, int cap2) {
    __shared__ int h[64];
    int bin = blockIdx.x;
    int t = threadIdx.x;
    if (t < 64) h[t] = 0;
    __syncthreads();
    int m = cnt2[bin];
    if (m > cap2) m = cap2;
    const uint32_t* buf = buf2 + (size_t)bin * cap2;
    for (int i = t; i < m; i += 256) atomicAdd(&h[buf[i] & 63], 1);
    __syncthreads();
    if (t < 64) {
        int node = bin * 64 + t;
        if (node < n) {
            cnt[node] = h[t];
            dinv[node] = rsqrtf((float)h[t] + 1.0f);
        }
    }
}

// ---------------- single-block exclusive scan over bin totals ----------------
__global__ __launch_bounds__(1024) void binScan_kernel(const int* __restrict__ cnt2,
                                                       int* __restrict__ binBase,
                                                       int NB, int cap2) {
    __shared__ int sm[1024];
    int t = threadIdx.x;
    int K = (NB + 1023) / 1024;
    int s = 0;
    for (int i = 0; i < K; ++i) {
        int idx = t * K + i;
        if (idx < NB) s += min(cnt2[idx], cap2);
    }
    sm[t] = s;
    __syncthreads();
    for (int off = 1; off < 1024; off <<= 1) {
        int v = 0;
        if (t >= off) v = sm[t - off];
        __syncthreads();
        sm[t] += v;
        __syncthreads();
    }
    int base = (t == 0) ? 0 : sm[t - 1];
    for (int i = 0; i < K; ++i) {
        int idx = t * K + i;
        if (idx < NB) {
            binBase[idx] = base;
            base += min(cnt2[idx], cap2);
        }
    }
}

// ---------------- scatter bin records into CSR + write rowend ----------------
__global__ __launch_bounds__(256) void binC_kernel(const int* __restrict__ cnt2,
                                                   const uint32_t* __restrict__ buf2,
                                                   const int* __restrict__ binBase,
                                                   const int* __restrict__ cnt,
                                                   int* __restrict__ rowend,
                                                   int* __restrict__ col, int n, int cap2) {
    __shared__ int rowst[64];
    __shared__ int cur[64];
    __shared__ int sc[64];
    int bin = blockIdx.x;
    int t = threadIdx.x;
    int c = 0;
    if (t < 64) {
        int node = bin * 64 + t;
        c = (node < n) ? cnt[node] : 0;
        sc[t] = c;
        cur[t] = 0;
    }
    __syncthreads();
    for (int off = 1; off < 64; off <<= 1) {
        int v = 0;
        if (t < 64 && t >= off) v = sc[t - off];
        __syncthreads();
        if (t < 64) sc[t] += v;
        __syncthreads();
    }
    if (t < 64) {
        int node = bin * 64 + t;
        int rs = binBase[bin] + sc[t] - c;   // exclusive local prefix
        rowst[t] = rs;
        if (node < n) rowend[node] = rs + c;
    }
    __syncthreads();
    int m = cnt2[bin];
    if (m > cap2) m = cap2;
    const uint32_t* buf = buf2 + (size_t)bin * cap2;
    for (int i = t; i < m; i += 256) {
        uint32_t rec = buf[i];
        int d6 = rec & 63;
        int off = atomicAdd(&cur[d6], 1);
        col[rowst[d6] + off] = (int)(rec >> 6);
    }
}

// ---------------- W -> fragment-ordered bf16 ----------------
__global__ __launch_bounds__(256) void wconv_all(const float* __restrict__ W1,
                                                 const float* __restrict__ W2,
                                                 const float* __restrict__ W3,
                                                 unsigned short* __restrict__ Wf1,
                                                 unsigned short* __restrict__ Wf2,
                                                 unsigned short* __restrict__ Wf3) {
    int idx = blockIdx.x * 256 + threadIdx.x;
    const float* W;
    unsigned short* Wf;
    int NCOL, base;
    if (idx < 2048)      { W = W1; Wf = Wf1; NCOL = 128; base = idx; }
    else if (idx < 4096) { W = W2; Wf = Wf2; NCOL = 128; base = idx - 2048; }
    else if (idx < 5120) { W = W3; Wf = Wf3; NCOL = 64;  base = idx - 4096; }
    else return;
    int f = base >> 6, l = base & 63;
    int ct = f >> 2, ks = f & 3;
    int nn = ct * 16 + (l & 15);
    int k0 = ks * 32 + (l >> 4) * 8;
    uint32_t pk[4];
#pragma unroll
    for (int j = 0; j < 4; ++j) {
        float a = W[(size_t)(k0 + 2 * j) * NCOL + nn];
        float b = W[(size_t)(k0 + 2 * j + 1) * NCOL + nn];
        pk[j] = f2_to_bf2(a, b);
    }
    uint4 v = make_uint4(pk[0], pk[1], pk[2], pk[3]);
    ((uint4*)Wf)[base] = v;
}

// ---------------- MFMA GEMM + dinv row-scale epilogue; OUT_FP8 packs e4m3 ----------
template <int NCOL, int A_FP32, int OUT_FP8>
__global__ __launch_bounds__(256) void gemm_mfma(const void* __restrict__ Av,
                                                 const unsigned short* __restrict__ Wf,
                                                 const float* __restrict__ dinv,
                                                 void* __restrict__ Cv, int n) {
    __shared__ unsigned short lds[NCOL * 128];
    const int t = threadIdx.x;
    for (int i = t; i < NCOL * 16; i += 256)
        ((uint4*)lds)[i] = ((const uint4*)Wf)[i];
    __syncthreads();

    const int wave = t >> 6, lane = t & 63;
    const int row0 = blockIdx.x * 64 + wave * 16;
    const int m = lane & 15, quad = lane >> 4;
    int arow = row0 + m;
    if (arow >= n) arow = n - 1;

    short8v a[4];
    if (A_FP32) {
        const float* A = (const float*)Av;
#pragma unroll
        for (int ks = 0; ks < 4; ++ks) {
            float4 lo = *(const float4*)(A + (size_t)arow * 128 + ks * 32 + quad * 8);
            float4 hi = *(const float4*)(A + (size_t)arow * 128 + ks * 32 + quad * 8 + 4);
            union { short8v v; uint32_t u[4]; } pk;
            pk.u[0] = f2_to_bf2(lo.x, lo.y);
            pk.u[1] = f2_to_bf2(lo.z, lo.w);
            pk.u[2] = f2_to_bf2(hi.x, hi.y);
            pk.u[3] = f2_to_bf2(hi.z, hi.w);
            a[ks] = pk.v;
        }
    } else {
        const unsigned short* A = (const unsigned short*)Av;
#pragma unroll
        for (int ks = 0; ks < 4; ++ks)
            a[ks] = *(const short8v*)(A + (size_t)arow * 128 + ks * 32 + quad * 8);
    }

    const int cr0 = row0 + quad * 4;
    float ds[4];
#pragma unroll
    for (int r = 0; r < 4; ++r) {
        int gr = cr0 + r;
        ds[r] = (gr < n) ? dinv[gr] : 0.0f;
    }
#pragma unroll
    for (int ct = 0; ct < NCOL / 16; ++ct) {
        float4v acc = {0.0f, 0.0f, 0.0f, 0.0f};
#pragma unroll
        for (int ks = 0; ks < 4; ++ks) {
            int f = ct * 4 + ks;
            short8v b = *(const short8v*)(lds + ((size_t)(f * 64 + lane)) * 8);
            acc = __builtin_amdgcn_mfma_f32_16x16x32_bf16(a[ks], b, acc, 0, 0, 0);
        }
#pragma unroll
        for (int r = 0; r < 4; ++r) {
            int gr = cr0 + r;
            if (gr < n) {
                float val = acc[r] * ds[r];
                if (OUT_FP8) {
                    int u = __builtin_amdgcn_cvt_pk_fp8_f32(val, val, 0, false);
                    ((unsigned char*)Cv)[(size_t)gr * NCOL + ct * 16 + m] =
                        (unsigned char)(u & 0xFF);
                } else {
                    ((unsigned short*)Cv)[(size_t)gr * NCOL + ct * 16 + m] = f_to_bf(val);
                }
            }
        }
    }
}

// ---------------- 2-node aggregation, 128 feats, fp8 T (128B rows) ----------------
// sel=lane>>5 (node), slot=(lane>>3)&3 (4 edge slots), j=lane&7 (16-feat octet).
__global__ __launch_bounds__(256) void agg_relu_128_fp8(
        const uint32_t* __restrict__ T8, const int* __restrict__ rowend,
        const int* __restrict__ cnt, const int* __restrict__ col,
        const float* __restrict__ dinv, const float* __restrict__ bias,
        uint32_t* __restrict__ outHb, int n) {
    int wid = blockIdx.x * 4 + (threadIdx.x >> 6);
    int lane = threadIdx.x & 63;
    int sel = lane >> 5, slot = (lane >> 3) & 3, j = lane & 7;
    int nodeA = wid * 2;
    int node = nodeA + sel;
    if (nodeA >= n) return;
    bool valid = node < n;
    int nd = valid ? node : nodeA;
    int end = rowend[nd];
    int start = end - cnt[nd];
    if (!valid) start = end;

    float acc[16];
#pragma unroll
    for (int k = 0; k < 16; ++k) acc[k] = 0.0f;
    if (slot == 0 && valid) {
        uint4 v = *(const uint4*)(T8 + (size_t)node * 32 + j * 4);
        acc16_fp8_fma(acc, v, 1.0f);
    }
    int deg = end - start;
    int degM = max(deg, __shfl_xor(deg, 32, 64));
    int p = start + slot;
    for (int it = 0; it < degM; it += 8) {
        int e0 = p, e1 = p + 4;
        float w0 = e0 < end ? 1.0f : 0.0f;
        float w1 = e1 < end ? 1.0f : 0.0f;
        int c0 = min(e0, end - 1); c0 = max(c0, 0);
        int c1 = min(e1, end - 1); c1 = max(c1, 0);
        int s0 = col[c0], s1 = col[c1];
        uint4 v0 = *(const uint4*)(T8 + (size_t)s0 * 32 + j * 4);
        uint4 v1 = *(const uint4*)(T8 + (size_t)s1 * 32 + j * 4);
        acc16_fp8_fma(acc, v0, w0);
        acc16_fp8_fma(acc, v1, w1);
        p += 8;
    }
    // reduce across the 4 slots within each half (lane bits 3,4)
#pragma unroll
    for (int k = 0; k < 16; ++k) {
        acc[k] += __shfl_xor(acc[k], 8, 64);
        acc[k] += __shfl_xor(acc[k], 16, 64);
    }
    if (slot == 0 && valid) {
        float di = dinv[node];
        const float4* b4 = (const float4*)bias;
        float r[16];
#pragma unroll
        for (int q = 0; q < 4; ++q) {
            float4 bb = b4[j * 4 + q];
            r[q * 4 + 0] = fmaxf(di * acc[q * 4 + 0] + bb.x, 0.0f);
            r[q * 4 + 1] = fmaxf(di * acc[q * 4 + 1] + bb.y, 0.0f);
            r[q * 4 + 2] = fmaxf(di * acc[q * 4 + 2] + bb.z, 0.0f);
            r[q * 4 + 3] = fmaxf(di * acc[q * 4 + 3] + bb.w, 0.0f);
        }
        uint4 o0, o1;
        o0.x = f2_to_bf2(r[0], r[1]);   o0.y = f2_to_bf2(r[2], r[3]);
        o0.z = f2_to_bf2(r[4], r[5]);   o0.w = f2_to_bf2(r[6], r[7]);
        o1.x = f2_to_bf2(r[8], r[9]);   o1.y = f2_to_bf2(r[10], r[11]);
        o1.z = f2_to_bf2(r[12], r[13]); o1.w = f2_to_bf2(r[14], r[15]);
        *(uint4*)(outHb + (size_t)node * 64 + j * 8) = o0;
        *(uint4*)(outHb + (size_t)node * 64 + j * 8 + 4) = o1;
    }
}

// ---------------- 2-node aggregation, 64 feats bf16 + log_softmax ----------------
__global__ __launch_bounds__(256) void agg_lsm_64_w2(
        const unsigned short* __restrict__ T, const int* __restrict__ rowend,
        const int* __restrict__ cnt, const int* __restrict__ col,
        const float* __restrict__ dinv, const float* __restrict__ bias,
        float* __restrict__ out, int n) {
    int wid = blockIdx.x * 4 + (threadIdx.x >> 6);
    int lane = threadIdx.x & 63;
    int sel = lane >> 5, slot = (lane >> 3) & 3, j = lane & 7;
    int node = wid * 2 + sel;
    int nodeA = wid * 2;
    if (nodeA >= n) return;
    bool valid = node < n;
    int nd = valid ? node : nodeA;
    int end = rowend[nd];
    int start = end - cnt[nd];
    if (!valid) start = end;

    float acc[8];
#pragma unroll
    for (int k = 0; k < 8; ++k) acc[k] = 0.0f;
    if (slot == 0 && valid) {
        uint4 v = *(const uint4*)(T + (size_t)node * 64 + j * 8);
        acc8_fma(acc, v, 1.0f);
    }
    int deg = end - start;
    int degM = max(deg, __shfl_xor(deg, 32, 64));
    int p = start + slot;
    for (int it = 0; it < degM; it += 8) {
        int e0 = p, e1 = p + 4;
        float w0 = e0 < end ? 1.0f : 0.0f;
        float w1 = e1 < end ? 1.0f : 0.0f;
        int c0 = min(e0, end - 1); c0 = max(c0, 0);
        int c1 = min(e1, end - 1); c1 = max(c1, 0);
        int s0 = col[c0], s1 = col[c1];
        uint4 v0 = *(const uint4*)(T + (size_t)s0 * 64 + j * 8);
        uint4 v1 = *(const uint4*)(T + (size_t)s1 * 64 + j * 8);
        acc8_fma(acc, v0, w0);
        acc8_fma(acc, v1, w1);
        p += 8;
    }
#pragma unroll
    for (int k = 0; k < 8; ++k) {
        acc[k] += __shfl_xor(acc[k], 8, 64);
        acc[k] += __shfl_xor(acc[k], 16, 64);
    }
    float di = dinv[nd];
    const float4* b4 = (const float4*)bias;
    float4 ba = b4[j * 2], bb = b4[j * 2 + 1];
    float r[8];
    r[0] = di * acc[0] + ba.x; r[1] = di * acc[1] + ba.y;
    r[2] = di * acc[2] + ba.z; r[3] = di * acc[3] + ba.w;
    r[4] = di * acc[4] + bb.x; r[5] = di * acc[5] + bb.y;
    r[6] = di * acc[6] + bb.z; r[7] = di * acc[7] + bb.w;
    float m = r[0];
#pragma unroll
    for (int k = 1; k < 8; ++k) m = fmaxf(m, r[k]);
    m = fmaxf(m, __shfl_xor(m, 1, 64));
    m = fmaxf(m, __shfl_xor(m, 2, 64));
    m = fmaxf(m, __shfl_xor(m, 4, 64));
    float ss = 0.0f;
#pragma unroll
    for (int k = 0; k < 8; ++k) ss += expf(r[k] - m);
    ss += __shfl_xor(ss, 1, 64);
    ss += __shfl_xor(ss, 2, 64);
    ss += __shfl_xor(ss, 4, 64);
    float lg = m + logf(ss);
    if (slot == 0 && valid) {
        float4 o0 = make_float4(r[0] - lg, r[1] - lg, r[2] - lg, r[3] - lg);
        float4 o1 = make_float4(r[4] - lg, r[5] - lg, r[6] - lg, r[7] - lg);
        *(float4*)(out + (size_t)node * 64 + j * 8) = o0;
        *(float4*)(out + (size_t)node * 64 + j * 8 + 4) = o1;
    }
}

// ---------------- launcher ----------------
extern "C" void kernel_launch(void* const* d_in, const int* in_sizes, int n_in,
                              void* d_out, int out_size, void* d_ws, size_t ws_size,
                              hipStream_t stream) {
    const float* x  = (const float*)d_in[0];
    const void*  ei = d_in[1];
    const float* W1 = (const float*)d_in[2];
    const float* b1 = (const float*)d_in[3];
    const float* W2 = (const float*)d_in[4];
    const float* b2 = (const float*)d_in[5];
    const float* W3 = (const float*)d_in[6];
    const float* b3 = (const float*)d_in[7];
    float* out = (float*)d_out;

    const int n = in_sizes[0] / FIN;       // 100000
    const int E = in_sizes[1] / 2;         // 1600000

    char* p = (char*)d_ws;
    auto carve = [&](size_t bytes) {
        char* q = p;
        p += (bytes + 255) & ~(size_t)255;
        return q;
    };
    const int NB = (n + 63) / 64;          // 64-node bins
    const int NS = (n + 8191) / 8192;      // 8192-node super-bins

    int*   cnt     = (int*)carve((size_t)n * 4);
    int*   rowend  = (int*)carve((size_t)n * 4);
    float* dinv    = (float*)carve((size_t)n * 4);
    int*   colb    = (int*)carve((size_t)E * 4);
    int*   gCnt    = (int*)carve((size_t)(16 + NB) * 4);   // gCnt + cnt2, one memset
    int*   cnt2    = gCnt + 16;
    int*   binBase = (int*)carve((size_t)NB * 4);
    // T: fp8 n*128 (layers 1-2) == bf16 n*64 (layer 3) == 12.8MB; Hb bf16 25.6MB.
    // Split bufs alias the combined T+Hb region (free during preprocessing).
    size_t Tbytes = (size_t)n * 128;
    size_t Hbytes = (size_t)n * 128 * 2;
    char*  TH = carve(Tbytes + Hbytes);
    void*  T  = (void*)TH;
    unsigned short* Hb = (unsigned short*)(TH + Tbytes);
    unsigned short* Wf1 = (unsigned short*)carve(128 * 128 * 2);
    unsigned short* Wf2 = (unsigned short*)carve(128 * 128 * 2);
    unsigned short* Wf3 = (unsigned short*)carve(128 * 64 * 2);

    long long meanS = (long long)E * 8192 / n;
    int capS = (int)(meanS + 8 * (long long)sqrt((double)meanS) + 1024);
    capS = (capS + 15) & ~15;
    long long mean2 = (long long)E * 64 / n;
    int cap2 = (int)(mean2 + 8 * (long long)sqrt((double)mean2) + 64);
    cap2 = (cap2 + 15) & ~15;
    size_t buf1B = ((size_t)NS * capS * 8 + 255) & ~(size_t)255;
    uint2*    buf1 = (uint2*)TH;
    uint32_t* buf2 = (uint32_t*)(TH + buf1B);
    size_t avail2 = (Tbytes + Hbytes > buf1B) ? (Tbytes + Hbytes - buf1B) : 0;
    size_t maxc2 = avail2 / ((size_t)NB * 4);
    if ((size_t)cap2 > maxc2) cap2 = (int)maxc2;

    hipMemsetAsync(gCnt, 0, (size_t)(16 + NB) * 4, stream);

    const int gagg2 = ((n + 1) / 2 + 3) / 4;     // 2 nodes per wave
    const int ggemm = (n + 63) / 64;
    const int gsplitA = (E + SP_CHUNK - 1) / SP_CHUNK;
    const int gsplitBx = (capS + SP_CHUNK - 1) / SP_CHUNK;

    splitA_kernel<<<gsplitA, 256, 0, stream>>>(ei, gCnt, buf1, E, capS);
    splitB_kernel<<<dim3(gsplitBx, NS), 256, 0, stream>>>(gCnt, buf1, cnt2, buf2, capS,
                                                          cap2, NB);
    binB_kernel<<<NB, 256, 0, stream>>>(cnt2, buf2, cnt, dinv, n, cap2);
    binScan_kernel<<<1, 1024, 0, stream>>>(cnt2, binBase, NB, cap2);
    binC_kernel<<<NB, 256, 0, stream>>>(cnt2, buf2, binBase, cnt, rowend, colb, n, cap2);
    wconv_all<<<20, 256, 0, stream>>>(W1, W2, W3, Wf1, Wf2, Wf3);

    // layer 1: T(fp8) = dinv * (x @ W1) ; Hb(bf16) = relu(di*(sum T) + b1)
    gemm_mfma<128, 1, 1><<<ggemm, 256, 0, stream>>>(x, Wf1, dinv, T, n);
    agg_relu_128_fp8<<<gagg2, 256, 0, stream>>>((const uint32_t*)T, rowend, cnt, colb,
                                                dinv, b1, (uint32_t*)Hb, n);
    // layer 2
    gemm_mfma<128, 0, 1><<<ggemm, 256, 0, stream>>>(Hb, Wf2, dinv, T, n);
    agg_relu_128_fp8<<<gagg2, 256, 0, stream>>>((const uint32_t*)T, rowend, cnt, colb,
                                                dinv, b2, (uint32_t*)Hb, n);
    // layer 3: T(bf16) = dinv * (Hb @ W3) ; out = log_softmax(...)
    gemm_mfma<64, 0, 0><<<ggemm, 256, 0, stream>>>(Hb, Wf3, dinv, T, n);
    agg_lsm_64_w2<<<gagg2, 256, 0, stream>>>((const unsigned short*)T, rowend, cnt,
                                             colb, dinv, b3, out, n);
}

// Round 10
// 304.861 us; speedup vs baseline: 2.4217x; 1.0020x over previous
//
#include <hip/hip_runtime.h>
#include <stdint.h>
#include <math.h>

#define FIN 128

typedef __attribute__((ext_vector_type(8))) short short8v;
typedef __attribute__((ext_vector_type(4))) float float4v;
typedef __attribute__((ext_vector_type(2))) float float2v;

// ---------------- bf16 helpers (manual, RNE) ----------------
__device__ __forceinline__ float2 bf2_to_f2(uint32_t u) {
    union { uint32_t i; float f; } a, b;
    a.i = (u & 0xFFFFu) << 16;
    b.i = u & 0xFFFF0000u;
    return make_float2(a.f, b.f);
}
__device__ __forceinline__ uint32_t f2_to_bf2(float x, float y) {
    union { float f; uint32_t i; } a, b;
    a.f = x; b.f = y;
    uint32_t ax = a.i + 0x7FFF + ((a.i >> 16) & 1);
    uint32_t by = b.i + 0x7FFF + ((b.i >> 16) & 1);
    return (ax >> 16) | (by & 0xFFFF0000u);
}
__device__ __forceinline__ unsigned short f_to_bf(float x) {
    union { float f; uint32_t i; } a;
    a.f = x;
    uint32_t u = a.i + 0x7FFF + ((a.i >> 16) & 1);
    return (unsigned short)(u >> 16);
}
// acc2[0..7] (+)= 16 fp8 decoded (packed adds); caller pre-zeroes v for masking
__device__ __forceinline__ void acc16_fp8_pk(float2v* acc2, uint4 v) {
    uint32_t us[4] = {v.x, v.y, v.z, v.w};
#pragma unroll
    for (int q = 0; q < 4; ++q) {
        acc2[q * 2 + 0] += __builtin_amdgcn_cvt_pk_f32_fp8(us[q], false);
        acc2[q * 2 + 1] += __builtin_amdgcn_cvt_pk_f32_fp8(us[q], true);
    }
}

__device__ __forceinline__ int edge_at(const void* ei, long long idx, int is32) {
    return is32 ? ((const int*)ei)[idx] : (int)((const long long*)ei)[idx];
}

// ---------------- Level-1 split (16 super-bins, dst>>13) + inline dtype detect ------
// record = (src<<13)|(dst&8191), 30 bits (requires n < 2^19; here n = 100000)
#define SP_CHUNK 4096
__global__ __launch_bounds__(256) void splitA_kernel(const void* __restrict__ ei,
                                                     int* __restrict__ gCnt,
                                                     uint32_t* __restrict__ buf1,
                                                     int E, int capS) {
    __shared__ int hist[16];
    __shared__ int gbase[16];
    __shared__ int lflag;
    int t = threadIdx.x;
    if (t < 16) hist[t] = 0;
    if (t == 0) lflag = 0;
    long long base = (long long)blockIdx.x * SP_CHUNK;
    __syncthreads();
    {
        long long e = base + t;
        if (e < E && ((const int*)ei)[2 * e + 1] != 0) atomicOr(&lflag, 1);
    }
    __syncthreads();
    int is32 = lflag;
    uint32_t lrec[16], rec[16];
#pragma unroll
    for (int j = 0; j < 16; ++j) {
        long long e = base + t + j * 256;
        if (e < E) {
            int s = edge_at(ei, e, is32);
            int d = edge_at(ei, (long long)E + e, is32);
            int b = d >> 13;
            int lofs = atomicAdd(&hist[b], 1);
            lrec[j] = ((uint32_t)lofs << 4) | (uint32_t)b;
            rec[j] = ((uint32_t)s << 13) | (uint32_t)(d & 8191);
        } else
            lrec[j] = 0xFFFFFFFFu;
    }
    __syncthreads();
    if (t < 16) gbase[t] = atomicAdd(&gCnt[t], hist[t]);
    __syncthreads();
#pragma unroll
    for (int j = 0; j < 16; ++j) {
        if (lrec[j] != 0xFFFFFFFFu) {
            int b = lrec[j] & 15;
            int pos = gbase[b] + (int)(lrec[j] >> 4);
            if (pos < capS) buf1[(size_t)b * capS + pos] = rec[j];
        }
    }
}

// ---------------- Level-2 split: 128 sub-bins of 64 nodes ----------------
__global__ __launch_bounds__(256) void splitB_kernel(const int* __restrict__ gCnt,
                                                     const uint32_t* __restrict__ buf1,
                                                     int* __restrict__ cnt2,
                                                     uint32_t* __restrict__ buf2,
                                                     int capS, int cap2, int NB) {
    __shared__ int hist[128];
    __shared__ int gbase[128];
    int t = threadIdx.x;
    int s = blockIdx.y;
    if (t < 128) hist[t] = 0;
    __syncthreads();
    int m = gCnt[s];
    if (m > capS) m = capS;
    long long base = (long long)blockIdx.x * SP_CHUNK;
    uint32_t lrec[16], r32[16];
#pragma unroll
    for (int j = 0; j < 16; ++j) {
        long long i = base + t + j * 256;
        if (i < m) {
            uint32_t r = buf1[(size_t)s * capS + i];
            int d13 = (int)(r & 8191u);
            int sub = d13 >> 6;
            int lofs = atomicAdd(&hist[sub], 1);
            lrec[j] = ((uint32_t)lofs << 7) | (uint32_t)sub;
            r32[j] = ((r >> 13) << 6) | (uint32_t)(d13 & 63);
        } else
            lrec[j] = 0xFFFFFFFFu;
    }
    __syncthreads();
    if (t < 128) {
        int g = s * 128 + t;
        gbase[t] = (g < NB) ? atomicAdd(&cnt2[g], hist[t]) : 0;
    }
    __syncthreads();
#pragma unroll
    for (int j = 0; j < 16; ++j) {
        if (lrec[j] != 0xFFFFFFFFu) {
            int sub = lrec[j] & 127;
            int pos = gbase[sub] + (int)(lrec[j] >> 7);
            if (pos < cap2) buf2[(size_t)(s * 128 + sub) * cap2 + pos] = r32[j];
        }
    }
}

// ---------------- merged: degree+dinv+rowend (fixed bin-base) + CSR scatter --------
// col region for bin = [bin*cap2, bin*cap2+m); no global scan needed.
__global__ __launch_bounds__(256) void binBC_kernel(const int* __restrict__ cnt2,
                                                    const uint32_t* __restrict__ buf2,
                                                    int* __restrict__ cnt,
                                                    float* __restrict__ dinv,
                                                    int* __restrict__ rowend,
                                                    int* __restrict__ col,
                                                    int n, int cap2) {
    __shared__ int h[64];
    __shared__ int rowst[64];
    __shared__ int cur[64];
    __shared__ int sc[64];
    int bin = blockIdx.x;
    int t = threadIdx.x;
    if (t < 64) { h[t] = 0; cur[t] = 0; }
    __syncthreads();
    int m = cnt2[bin];
    if (m > cap2) m = cap2;
    const uint32_t* buf = buf2 + (size_t)bin * cap2;
    for (int i = t; i < m; i += 256) atomicAdd(&h[buf[i] & 63], 1);
    __syncthreads();
    int c = 0;
    if (t < 64) { c = h[t]; sc[t] = c; }
    __syncthreads();
    for (int off = 1; off < 64; off <<= 1) {
        int v = 0;
        if (t < 64 && t >= off) v = sc[t - off];
        __syncthreads();
        if (t < 64) sc[t] += v;
        __syncthreads();
    }
    if (t < 64) {
        int node = bin * 64 + t;
        int base = bin * cap2;
        rowst[t] = base + sc[t] - c;
        if (node < n) {
            cnt[node] = c;
            dinv[node] = rsqrtf((float)c + 1.0f);
            rowend[node] = base + sc[t];
        }
    }
    __syncthreads();
    for (int i = t; i < m; i += 256) {
        uint32_t rec = buf[i];
        int d6 = rec & 63;
        int off = atomicAdd(&cur[d6], 1);
        col[rowst[d6] + off] = (int)(rec >> 6);
    }
}

// ---------------- W -> fragment-ordered bf16 ----------------
__global__ __launch_bounds__(256) void wconv_all(const float* __restrict__ W1,
                                                 const float* __restrict__ W2,
                                                 const float* __restrict__ W3,
                                                 unsigned short* __restrict__ Wf1,
                                                 unsigned short* __restrict__ Wf2,
                                                 unsigned short* __restrict__ Wf3) {
    int idx = blockIdx.x * 256 + threadIdx.x;
    const float* W;
    unsigned short* Wf;
    int NCOL, base;
    if (idx < 2048)      { W = W1; Wf = Wf1; NCOL = 128; base = idx; }
    else if (idx < 4096) { W = W2; Wf = Wf2; NCOL = 128; base = idx - 2048; }
    else if (idx < 5120) { W = W3; Wf = Wf3; NCOL = 64;  base = idx - 4096; }
    else return;
    int f = base >> 6, l = base & 63;
    int ct = f >> 2, ks = f & 3;
    int nn = ct * 16 + (l & 15);
    int k0 = ks * 32 + (l >> 4) * 8;
    uint32_t pk[4];
#pragma unroll
    for (int j = 0; j < 4; ++j) {
        float a = W[(size_t)(k0 + 2 * j) * NCOL + nn];
        float b = W[(size_t)(k0 + 2 * j + 1) * NCOL + nn];
        pk[j] = f2_to_bf2(a, b);
    }
    uint4 v = make_uint4(pk[0], pk[1], pk[2], pk[3]);
    ((uint4*)Wf)[base] = v;
}

// ---------------- MFMA GEMM + dinv row-scale epilogue; OUT_FP8 packs e4m3 ----------
template <int NCOL, int A_FP32, int OUT_FP8>
__global__ __launch_bounds__(256) void gemm_mfma(const void* __restrict__ Av,
                                                 const unsigned short* __restrict__ Wf,
                                                 const float* __restrict__ dinv,
                                                 void* __restrict__ Cv, int n) {
    __shared__ unsigned short lds[NCOL * 128];
    const int t = threadIdx.x;
    for (int i = t; i < NCOL * 16; i += 256)
        ((uint4*)lds)[i] = ((const uint4*)Wf)[i];
    __syncthreads();

    const int wave = t >> 6, lane = t & 63;
    const int row0 = blockIdx.x * 64 + wave * 16;
    const int m = lane & 15, quad = lane >> 4;
    int arow = row0 + m;
    if (arow >= n) arow = n - 1;

    short8v a[4];
    if (A_FP32) {
        const float* A = (const float*)Av;
#pragma unroll
        for (int ks = 0; ks < 4; ++ks) {
            float4 lo = *(const float4*)(A + (size_t)arow * 128 + ks * 32 + quad * 8);
            float4 hi = *(const float4*)(A + (size_t)arow * 128 + ks * 32 + quad * 8 + 4);
            union { short8v v; uint32_t u[4]; } pk;
            pk.u[0] = f2_to_bf2(lo.x, lo.y);
            pk.u[1] = f2_to_bf2(lo.z, lo.w);
            pk.u[2] = f2_to_bf2(hi.x, hi.y);
            pk.u[3] = f2_to_bf2(hi.z, hi.w);
            a[ks] = pk.v;
        }
    } else {
        const unsigned short* A = (const unsigned short*)Av;
#pragma unroll
        for (int ks = 0; ks < 4; ++ks)
            a[ks] = *(const short8v*)(A + (size_t)arow * 128 + ks * 32 + quad * 8);
    }

    const int cr0 = row0 + quad * 4;
    float ds[4];
#pragma unroll
    for (int r = 0; r < 4; ++r) {
        int gr = cr0 + r;
        ds[r] = (gr < n) ? dinv[gr] : 0.0f;
    }
#pragma unroll
    for (int ct = 0; ct < NCOL / 16; ++ct) {
        float4v acc = {0.0f, 0.0f, 0.0f, 0.0f};
#pragma unroll
        for (int ks = 0; ks < 4; ++ks) {
            int f = ct * 4 + ks;
            short8v b = *(const short8v*)(lds + ((size_t)(f * 64 + lane)) * 8);
            acc = __builtin_amdgcn_mfma_f32_16x16x32_bf16(a[ks], b, acc, 0, 0, 0);
        }
#pragma unroll
        for (int r = 0; r < 4; ++r) {
            int gr = cr0 + r;
            if (gr < n) {
                float val = acc[r] * ds[r];
                if (OUT_FP8) {
                    int u = __builtin_amdgcn_cvt_pk_fp8_f32(val, val, 0, false);
                    ((unsigned char*)Cv)[(size_t)gr * NCOL + ct * 16 + m] =
                        (unsigned char)(u & 0xFF);
                } else {
                    ((unsigned short*)Cv)[(size_t)gr * NCOL + ct * 16 + m] = f_to_bf(val);
                }
            }
        }
    }
}

// ---------------- 2-node aggregation, 128 feats, fp8 T (128B rows) ----------------
// sel=lane>>5 (node), slot=(lane>>3)&3 (4 edge slots), j=lane&7 (16-feat octet).
// Packed-float accumulation; masking via cndmask-zeroed loads (fp8 0x00 == 0.0).
__global__ __launch_bounds__(256) void agg_relu_128_fp8(
        const uint32_t* __restrict__ T8, const int* __restrict__ rowend,
        const int* __restrict__ cnt, const int* __restrict__ col,
        const float* __restrict__ dinv, const float* __restrict__ bias,
        uint32_t* __restrict__ outHb, int n) {
    int wid = blockIdx.x * 4 + (threadIdx.x >> 6);
    int lane = threadIdx.x & 63;
    int sel = lane >> 5, slot = (lane >> 3) & 3, j = lane & 7;
    int nodeA = wid * 2;
    int node = nodeA + sel;
    if (nodeA >= n) return;
    bool valid = node < n;
    int nd = valid ? node : nodeA;
    int end = rowend[nd];
    int start = end - cnt[nd];
    if (!valid) start = end;

    float2v acc2[8];
#pragma unroll
    for (int k = 0; k < 8; ++k) acc2[k] = (float2v){0.0f, 0.0f};
    if (slot == 0 && valid) {
        uint4 v = *(const uint4*)(T8 + (size_t)node * 32 + j * 4);
        acc16_fp8_pk(acc2, v);
    }
    int deg = end - start;
    int degM = max(deg, __shfl_xor(deg, 32, 64));
    int p = start + slot;
    const uint4 Z = make_uint4(0, 0, 0, 0);
    for (int it = 0; it < degM; it += 8) {
        int e0 = p, e1 = p + 4;
        bool k0 = e0 < end, k1 = e1 < end;
        int c0 = min(e0, end - 1); c0 = max(c0, 0);
        int c1 = min(e1, end - 1); c1 = max(c1, 0);
        int s0 = col[c0], s1 = col[c1];
        uint4 v0 = *(const uint4*)(T8 + (size_t)s0 * 32 + j * 4);
        uint4 v1 = *(const uint4*)(T8 + (size_t)s1 * 32 + j * 4);
        if (!k0) v0 = Z;
        if (!k1) v1 = Z;
        acc16_fp8_pk(acc2, v0);
        acc16_fp8_pk(acc2, v1);
        p += 8;
    }
    float* acc = (float*)acc2;
#pragma unroll
    for (int k = 0; k < 16; ++k) {
        acc[k] += __shfl_xor(acc[k], 8, 64);
        acc[k] += __shfl_xor(acc[k], 16, 64);
    }
    if (slot == 0 && valid) {
        float di = dinv[node];
        const float4* b4 = (const float4*)bias;
        float r[16];
#pragma unroll
        for (int q = 0; q < 4; ++q) {
            float4 bb = b4[j * 4 + q];
            r[q * 4 + 0] = fmaxf(di * acc[q * 4 + 0] + bb.x, 0.0f);
            r[q * 4 + 1] = fmaxf(di * acc[q * 4 + 1] + bb.y, 0.0f);
            r[q * 4 + 2] = fmaxf(di * acc[q * 4 + 2] + bb.z, 0.0f);
            r[q * 4 + 3] = fmaxf(di * acc[q * 4 + 3] + bb.w, 0.0f);
        }
        uint4 o0, o1;
        o0.x = f2_to_bf2(r[0], r[1]);   o0.y = f2_to_bf2(r[2], r[3]);
        o0.z = f2_to_bf2(r[4], r[5]);   o0.w = f2_to_bf2(r[6], r[7]);
        o1.x = f2_to_bf2(r[8], r[9]);   o1.y = f2_to_bf2(r[10], r[11]);
        o1.z = f2_to_bf2(r[12], r[13]); o1.w = f2_to_bf2(r[14], r[15]);
        *(uint4*)(outHb + (size_t)node * 64 + j * 8) = o0;
        *(uint4*)(outHb + (size_t)node * 64 + j * 8 + 4) = o1;
    }
}

// ---------------- 2-node aggregation, 64 feats fp8 (64B rows) + log_softmax --------
// sel=lane>>5, slot=(lane>>2)&7 (8 edge slots), j=lane&3 (16-feat octet of 64).
__global__ __launch_bounds__(256) void agg_lsm_64_fp8(
        const uint32_t* __restrict__ T8, const int* __restrict__ rowend,
        const int* __restrict__ cnt, const int* __restrict__ col,
        const float* __restrict__ dinv, const float* __restrict__ bias,
        float* __restrict__ out, int n) {
    int wid = blockIdx.x * 4 + (threadIdx.x >> 6);
    int lane = threadIdx.x & 63;
    int sel = lane >> 5, slot = (lane >> 2) & 7, j = lane & 3;
    int nodeA = wid * 2;
    int node = nodeA + sel;
    if (nodeA >= n) return;
    bool valid = node < n;
    int nd = valid ? node : nodeA;
    int end = rowend[nd];
    int start = end - cnt[nd];
    if (!valid) start = end;

    float2v acc2[8];
#pragma unroll
    for (int k = 0; k < 8; ++k) acc2[k] = (float2v){0.0f, 0.0f};
    if (slot == 0 && valid) {
        uint4 v = *(const uint4*)(T8 + (size_t)node * 16 + j * 4);
        acc16_fp8_pk(acc2, v);
    }
    int deg = end - start;
    int degM = max(deg, __shfl_xor(deg, 32, 64));
    int p = start + slot;
    const uint4 Z = make_uint4(0, 0, 0, 0);
    for (int it = 0; it < degM; it += 16) {
        int e0 = p, e1 = p + 8;
        bool k0 = e0 < end, k1 = e1 < end;
        int c0 = min(e0, end - 1); c0 = max(c0, 0);
        int c1 = min(e1, end - 1); c1 = max(c1, 0);
        int s0 = col[c0], s1 = col[c1];
        uint4 v0 = *(const uint4*)(T8 + (size_t)s0 * 16 + j * 4);
        uint4 v1 = *(const uint4*)(T8 + (size_t)s1 * 16 + j * 4);
        if (!k0) v0 = Z;
        if (!k1) v1 = Z;
        acc16_fp8_pk(acc2, v0);
        acc16_fp8_pk(acc2, v1);
        p += 16;
    }
    float* acc = (float*)acc2;
    // reduce across the 8 slots (lane bits 2,3,4)
#pragma unroll
    for (int k = 0; k < 16; ++k) {
        acc[k] += __shfl_xor(acc[k], 4, 64);
        acc[k] += __shfl_xor(acc[k], 8, 64);
        acc[k] += __shfl_xor(acc[k], 16, 64);
    }
    float di = dinv[nd];
    const float4* b4 = (const float4*)bias;
    float r[16];
#pragma unroll
    for (int q = 0; q < 4; ++q) {
        float4 bb = b4[j * 4 + q];
        r[q * 4 + 0] = di * acc[q * 4 + 0] + bb.x;
        r[q * 4 + 1] = di * acc[q * 4 + 1] + bb.y;
        r[q * 4 + 2] = di * acc[q * 4 + 2] + bb.z;
        r[q * 4 + 3] = di * acc[q * 4 + 3] + bb.w;
    }
    // log_softmax over 64 feats: 16 local + reduce over j (lane bits 0,1)
    float m = r[0];
#pragma unroll
    for (int k = 1; k < 16; ++k) m = fmaxf(m, r[k]);
    m = fmaxf(m, __shfl_xor(m, 1, 64));
    m = fmaxf(m, __shfl_xor(m, 2, 64));
    float ss = 0.0f;
#pragma unroll
    for (int k = 0; k < 16; ++k) ss += expf(r[k] - m);
    ss += __shfl_xor(ss, 1, 64);
    ss += __shfl_xor(ss, 2, 64);
    float lg = m + logf(ss);
    if (slot == 0 && valid) {
#pragma unroll
        for (int q = 0; q < 4; ++q) {
            float4 o = make_float4(r[q * 4 + 0] - lg, r[q * 4 + 1] - lg,
                                   r[q * 4 + 2] - lg, r[q * 4 + 3] - lg);
            *(float4*)(out + (size_t)node * 64 + j * 16 + q * 4) = o;
        }
    }
}

// ---------------- launcher ----------------
extern "C" void kernel_launch(void* const* d_in, const int* in_sizes, int n_in,
                              void* d_out, int out_size, void* d_ws, size_t ws_size,
                              hipStream_t stream) {
    const float* x  = (const float*)d_in[0];
    const void*  ei = d_in[1];
    const float* W1 = (const float*)d_in[2];
    const float* b1 = (const float*)d_in[3];
    const float* W2 = (const float*)d_in[4];
    const float* b2 = (const float*)d_in[5];
    const float* W3 = (const float*)d_in[6];
    const float* b3 = (const float*)d_in[7];
    float* out = (float*)d_out;

    const int n = in_sizes[0] / FIN;       // 100000
    const int E = in_sizes[1] / 2;         // 1600000

    char* p = (char*)d_ws;
    auto carve = [&](size_t bytes) {
        char* q = p;
        p += (bytes + 255) & ~(size_t)255;
        return q;
    };
    const int NB = (n + 63) / 64;
    const int NS = (n + 8191) / 8192;

    long long meanS = (long long)E * 8192 / n;
    int capS = (int)(meanS + 8 * (long long)sqrt((double)meanS) + 1024);
    capS = (capS + 15) & ~15;
    long long mean2 = (long long)E * 64 / n;
    int cap2 = (int)(mean2 + 8 * (long long)sqrt((double)mean2) + 64);
    cap2 = (cap2 + 15) & ~15;

    int*   cnt     = (int*)carve((size_t)n * 4);
    int*   rowend  = (int*)carve((size_t)n * 4);
    float* dinv    = (float*)carve((size_t)n * 4);
    int*   colb    = (int*)carve((size_t)NB * cap2 * 4);   // fixed per-bin windows
    int*   gCnt    = (int*)carve((size_t)(16 + NB) * 4);
    int*   cnt2    = gCnt + 16;
    // T: fp8 n*128 (layers 1-2; layer-3 n*64 fp8 fits inside); Hb bf16 n*128.
    size_t Tbytes = (size_t)n * 128;
    size_t Hbytes = (size_t)n * 128 * 2;
    char*  TH = carve(Tbytes + Hbytes);
    void*  T  = (void*)TH;
    unsigned short* Hb = (unsigned short*)(TH + Tbytes);
    unsigned short* Wf1 = (unsigned short*)carve(128 * 128 * 2);
    unsigned short* Wf2 = (unsigned short*)carve(128 * 128 * 2);
    unsigned short* Wf3 = (unsigned short*)carve(128 * 64 * 2);

    // split bufs alias the T+Hb region (free during preprocessing)
    size_t buf1B = ((size_t)NS * capS * 4 + 255) & ~(size_t)255;
    uint32_t* buf1 = (uint32_t*)TH;
    uint32_t* buf2 = (uint32_t*)(TH + buf1B);
    size_t avail2 = (Tbytes + Hbytes > buf1B) ? (Tbytes + Hbytes - buf1B) : 0;
    size_t maxc2 = avail2 / ((size_t)NB * 4);
    if ((size_t)cap2 > maxc2) cap2 = (int)maxc2;

    hipMemsetAsync(gCnt, 0, (size_t)(16 + NB) * 4, stream);

    const int gagg2 = ((n + 1) / 2 + 3) / 4;
    const int ggemm = (n + 63) / 64;
    const int gsplitA = (E + SP_CHUNK - 1) / SP_CHUNK;
    const int gsplitBx = (capS + SP_CHUNK - 1) / SP_CHUNK;

    splitA_kernel<<<gsplitA, 256, 0, stream>>>(ei, gCnt, buf1, E, capS);
    splitB_kernel<<<dim3(gsplitBx, NS), 256, 0, stream>>>(gCnt, buf1, cnt2, buf2, capS,
                                                          cap2, NB);
    binBC_kernel<<<NB, 256, 0, stream>>>(cnt2, buf2, cnt, dinv, rowend, colb, n, cap2);
    wconv_all<<<20, 256, 0, stream>>>(W1, W2, W3, Wf1, Wf2, Wf3);

    // layer 1: T(fp8) = dinv * (x @ W1) ; Hb(bf16) = relu(di*(sum T) + b1)
    gemm_mfma<128, 1, 1><<<ggemm, 256, 0, stream>>>(x, Wf1, dinv, T, n);
    agg_relu_128_fp8<<<gagg2, 256, 0, stream>>>((const uint32_t*)T, rowend, cnt, colb,
                                                dinv, b1, (uint32_t*)Hb, n);
    // layer 2
    gemm_mfma<128, 0, 1><<<ggemm, 256, 0, stream>>>(Hb, Wf2, dinv, T, n);
    agg_relu_128_fp8<<<gagg2, 256, 0, stream>>>((const uint32_t*)T, rowend, cnt, colb,
                                                dinv, b2, (uint32_t*)Hb, n);
    // layer 3: T(fp8, 64 cols) = dinv * (Hb @ W3) ; out = log_softmax(...)
    gemm_mfma<64, 0, 1><<<ggemm, 256, 0, stream>>>(Hb, Wf3, dinv, T, n);
    agg_lsm_64_fp8<<<gagg2, 256, 0, stream>>>((const uint32_t*)T, rowend, cnt, colb,
                                              dinv, b3, out, n);
}